// Round 9
// baseline (267.960 us; speedup 1.0000x reference)
//
#include <hip/hip_runtime.h>
#include <math.h>

#define B_SZ     2
#define L_SEQ    2048
#define DM       1024      // D_MODEL
#define DP       4384      // D_PROJ (logical)
#define PS       4480      // proj padded stride (35 * 128)
#define DI       2048      // D_INNER
#define NH       32        // N_HEADS
#define HD       64        // HEAD_DIM
#define DS       128       // D_STATE
#define M_ROWS   (B_SZ * L_SEQ)   // 4096
#define QCH      64        // scan chunk length
#define NC       (L_SEQ / QCH)    // 32 chunks

typedef __bf16 bf16x8 __attribute__((ext_vector_type(8)));
typedef __bf16 bf16x4 __attribute__((ext_vector_type(4)));
typedef __bf16 bf16x2 __attribute__((ext_vector_type(2)));
typedef float  f32x4  __attribute__((ext_vector_type(4)));

// async global->LDS, 16B per lane. LDS dest is wave-uniform base + lane*16.
__device__ __forceinline__ void gload16(const void* g, void* l) {
    __builtin_amdgcn_global_load_lds(
        (const __attribute__((address_space(1))) unsigned int*)g,
        (__attribute__((address_space(3))) unsigned int*)l,
        16, 0, 0);
}

// ---------------------------------------------------------------------------
// Fused: f2b(Wp) [blocks 0..4383] + RMSNorm [blocks 4384..8479]
// ---------------------------------------------------------------------------
__global__ __launch_bounds__(256) void k_prep(const float* __restrict__ Wp,
                                              __bf16* __restrict__ Wpb,
                                              const float* __restrict__ x,
                                              const float* __restrict__ w,
                                              __bf16* __restrict__ xn) {
    int tid = threadIdx.x;
    if (blockIdx.x < 4384) {
        int i = blockIdx.x * 256 + tid;          // < (DP*DM)/4
        float4 v = ((const float4*)Wp)[i];
        bf16x4 o = { (__bf16)v.x, (__bf16)v.y, (__bf16)v.z, (__bf16)v.w };
        ((bf16x4*)Wpb)[i] = o;
        return;
    }
    int row = blockIdx.x - 4384;
    const float4* x4 = (const float4*)(x + (long)row * DM);
    float4 v = x4[tid];
    float ss = v.x * v.x + v.y * v.y + v.z * v.z + v.w * v.w;
    #pragma unroll
    for (int off = 32; off > 0; off >>= 1) ss += __shfl_xor(ss, off, 64);
    __shared__ float sred[4];
    if ((tid & 63) == 0) sred[tid >> 6] = ss;
    __syncthreads();
    float tot = sred[0] + sred[1] + sred[2] + sred[3];
    float scale = rsqrtf(tot * (1.0f / (float)DM) + 1e-6f);
    const float4* w4 = (const float4*)w;
    float4 wv = w4[tid];
    bf16x4 o = { (__bf16)(v.x * scale * wv.x), (__bf16)(v.y * scale * wv.y),
                 (__bf16)(v.z * scale * wv.z), (__bf16)(v.w * scale * wv.w) };
    ((bf16x4*)(xn + (long)row * DM))[tid] = o;
}

// ---------------------------------------------------------------------------
// in_proj GEMM (PROVEN config — 63-76us across sessions, ~600 TF family
// ceiling; cross-session noise ~±10%, do not chase): 128x128 tile, BK=64,
// double-buffered global_load_lds, source-XOR swizzle -> 0 bank conflicts,
// counted-vmcnt schedule. NOTE (R3/R7): deeper/bigger structures at 1 blk/CU
// regress (103us, 89us). Do not re-attempt without the full 8-phase template.
// ---------------------------------------------------------------------------
__global__ __launch_bounds__(256) void k_gemm_bf(const __bf16* __restrict__ A,
                                                 const __bf16* __restrict__ W,
                                                 __bf16* __restrict__ Cb,
                                                 float* __restrict__ Dt,
                                                 int Nw, int K, int ldc) {
    __shared__ __align__(16) __bf16 As[2][128 * 64];
    __shared__ __align__(16) __bf16 Bs[2][128 * 64];
    int t = threadIdx.x;

    int gx = gridDim.x;
    int nwg = gx * gridDim.y;
    int orig = blockIdx.y * gx + blockIdx.x;
    int wgid = (nwg & 7) ? orig : ((orig & 7) * (nwg >> 3) + (orig >> 3));
    int bx = wgid % gx, by = wgid / gx;
    int bm = by * 128, bn = bx * 128;

    int lane = t & 63, w = t >> 6;

    int rl = lane >> 3;                  // row-in-8 (== row & 7 of target row)
    int lc = (lane & 7) ^ rl;            // pre-swizzled source logical chunk
    int rbase = w * 32 + rl;
    const __bf16* Agp[4];
    const __bf16* Wgp[4];
    #pragma unroll
    for (int i = 0; i < 4; i++) {
        Agp[i] = A + (long)(bm + rbase + i * 8) * K + lc * 8;
        int rb = bn + rbase + i * 8; if (rb >= Nw) rb = Nw - 1;
        Wgp[i] = W + (long)rb * K + lc * 8;
    }

    int wm = (w & 1) * 64, wn = (w >> 1) * 64;
    int ln = lane & 15;
    int q  = lane >> 4;

    f32x4 acc[4][4] = {};

    int nst = K >> 6;

    #pragma unroll
    for (int i = 0; i < 4; i++) {
        gload16(Agp[i], As[0] + (w * 4 + i) * 512);
        gload16(Wgp[i], Bs[0] + (w * 4 + i) * 512);
    }

    int cur = 0;
    for (int s = 0; s < nst; ++s) {
        if (s + 1 < nst) {
            long k1 = (long)(s + 1) << 6;
            #pragma unroll
            for (int i = 0; i < 4; i++) {
                gload16(Agp[i] + k1, As[cur ^ 1] + (w * 4 + i) * 512);
                gload16(Wgp[i] + k1, Bs[cur ^ 1] + (w * 4 + i) * 512);
            }
            asm volatile("s_waitcnt vmcnt(8)" ::: "memory");  // s done; s+1 in flight
        } else {
            asm volatile("s_waitcnt vmcnt(0)" ::: "memory");  // final tile: drain
        }
        __builtin_amdgcn_sched_barrier(0);
        __builtin_amdgcn_s_barrier();        // tile s visible to all waves
        __builtin_amdgcn_sched_barrier(0);
        __builtin_amdgcn_s_setprio(1);

        const __bf16* Asc = As[cur];
        const __bf16* Bsc = Bs[cur];
        #pragma unroll
        for (int h = 0; h < 2; h++) {
            int ch = (4 * h + q);
            int koff = ((ch ^ (ln & 7)) << 3);   // (R&7)==(ln&7): wm,i*16 ≡ 0 mod 8
            bf16x8 af[4], bfr[4];
            #pragma unroll
            for (int i = 0; i < 4; i++)
                af[i]  = *(const bf16x8*)(Asc + (wm + ln + i * 16) * 64 + koff);
            #pragma unroll
            for (int j = 0; j < 4; j++)
                bfr[j] = *(const bf16x8*)(Bsc + (wn + ln + j * 16) * 64 + koff);
            #pragma unroll
            for (int i = 0; i < 4; i++)
                #pragma unroll
                for (int j = 0; j < 4; j++)
                    acc[i][j] = __builtin_amdgcn_mfma_f32_16x16x32_bf16(
                                    af[i], bfr[j], acc[i][j], 0, 0, 0);
        }
        __builtin_amdgcn_s_setprio(0);
        __builtin_amdgcn_sched_barrier(0);
        __builtin_amdgcn_s_barrier();        // reads done before buf reuse
        __builtin_amdgcn_sched_barrier(0);
        cur ^= 1;
    }

    int colbase = bn + wn + ln;
    #pragma unroll
    for (int i = 0; i < 4; i++) {
        #pragma unroll
        for (int r = 0; r < 4; r++) {
            int m = bm + wm + i * 16 + (lane >> 4) * 4 + r;
            long off = (long)m * ldc + colbase;
            #pragma unroll
            for (int j = 0; j < 4; j++) {
                float v = acc[i][j][r];
                Cb[off + j * 16] = (__bf16)v;
                int col = colbase + j * 16;
                if (col >= 4352 && col < 4384)
                    Dt[(long)m * 32 + (col - 4352)] = v;
            }
        }
    }
}

// ---------------------------------------------------------------------------
// out_proj GEMM: BM=64 x BN=128 tile, BK=64 -> 512 blocks (2/CU). Counted
// vmcnt(6) schedule (proven R6: −18us vs 128² grid). Unchanged.
// ---------------------------------------------------------------------------
__global__ __launch_bounds__(256) void k_gemm_out(const __bf16* __restrict__ A,
                                                  const __bf16* __restrict__ W,
                                                  const float* __restrict__ resid,
                                                  float* __restrict__ Cf,
                                                  int K, int ldc) {
    __shared__ __align__(16) __bf16 As[2][64 * 64];
    __shared__ __align__(16) __bf16 Bs[2][128 * 64];
    int t = threadIdx.x;

    int gx = gridDim.x;                      // 8
    int nwg = gx * gridDim.y;                // 512 (%8==0 -> bijective)
    int orig = blockIdx.y * gx + blockIdx.x;
    int wgid = (nwg & 7) ? orig : ((orig & 7) * (nwg >> 3) + (orig >> 3));
    int bx = wgid % gx, by = wgid / gx;
    int bm = by * 64, bn = bx * 128;

    int lane = t & 63, w = t >> 6;

    int rl = lane >> 3;
    int lc = (lane & 7) ^ rl;                // pre-swizzled source chunk
    const __bf16* Agp[2];
    const __bf16* Wgp[4];
    #pragma unroll
    for (int i = 0; i < 2; i++)
        Agp[i] = A + (long)(bm + w * 16 + i * 8 + rl) * K + lc * 8;
    #pragma unroll
    for (int i = 0; i < 4; i++)
        Wgp[i] = W + (long)(bn + w * 32 + i * 8 + rl) * K + lc * 8;

    int wm = (w & 1) * 32, wn = (w >> 1) * 64;
    int ln = lane & 15;
    int q  = lane >> 4;

    f32x4 acc[2][4] = {};

    int nst = K >> 6;                        // 32

    #pragma unroll
    for (int i = 0; i < 2; i++) gload16(Agp[i], As[0] + (w * 2 + i) * 512);
    #pragma unroll
    for (int i = 0; i < 4; i++) gload16(Wgp[i], Bs[0] + (w * 4 + i) * 512);

    int cur = 0;
    for (int s = 0; s < nst; ++s) {
        if (s + 1 < nst) {
            long k1 = (long)(s + 1) << 6;
            #pragma unroll
            for (int i = 0; i < 2; i++)
                gload16(Agp[i] + k1, As[cur ^ 1] + (w * 2 + i) * 512);
            #pragma unroll
            for (int i = 0; i < 4; i++)
                gload16(Wgp[i] + k1, Bs[cur ^ 1] + (w * 4 + i) * 512);
            asm volatile("s_waitcnt vmcnt(6)" ::: "memory");
        } else {
            asm volatile("s_waitcnt vmcnt(0)" ::: "memory");
        }
        __builtin_amdgcn_sched_barrier(0);
        __builtin_amdgcn_s_barrier();
        __builtin_amdgcn_sched_barrier(0);
        __builtin_amdgcn_s_setprio(1);

        const __bf16* Asc = As[cur];
        const __bf16* Bsc = Bs[cur];
        #pragma unroll
        for (int h = 0; h < 2; h++) {
            int ch = (4 * h + q);
            int koff = ((ch ^ (ln & 7)) << 3);
            bf16x8 af[2], bfr[4];
            #pragma unroll
            for (int i = 0; i < 2; i++)
                af[i]  = *(const bf16x8*)(Asc + (wm + ln + i * 16) * 64 + koff);
            #pragma unroll
            for (int j = 0; j < 4; j++)
                bfr[j] = *(const bf16x8*)(Bsc + (wn + ln + j * 16) * 64 + koff);
            #pragma unroll
            for (int i = 0; i < 2; i++)
                #pragma unroll
                for (int j = 0; j < 4; j++)
                    acc[i][j] = __builtin_amdgcn_mfma_f32_16x16x32_bf16(
                                    af[i], bfr[j], acc[i][j], 0, 0, 0);
        }
        __builtin_amdgcn_s_setprio(0);
        __builtin_amdgcn_sched_barrier(0);
        __builtin_amdgcn_s_barrier();
        __builtin_amdgcn_sched_barrier(0);
        cur ^= 1;
    }

    int colbase = bn + wn + ln;
    #pragma unroll
    for (int i = 0; i < 2; i++) {
        #pragma unroll
        for (int r = 0; r < 4; r++) {
            int m = bm + wm + i * 16 + (lane >> 4) * 4 + r;
            long off = (long)m * ldc + colbase;
            #pragma unroll
            for (int j = 0; j < 4; j++) {
                float v = acc[i][j][r] + resid[off + j * 16];
                Cf[off + j * 16] = v;
            }
        }
    }
}

// ---------------------------------------------------------------------------
// Phase A (MFMA) fused conv+SiLU+dt/cumlog+D-term. NEW (R9): epilogue stores
// vectorized via band-local LDS bounce — each wave owns output rows
// 16w..16w+15, so compute-> ds_write (in-wave ordered after the fragment
// ds_reads) -> bf16x8 read-back -> 16B/lane coalesced global store, with NO
// added barriers. yssm bounces through sXCM (maf fragments read first, same
// band); Sloc bounces through sB (dead after transpose; the existing
// "sU complete" barrier orders all cross-wave sB reads before overwrite).
// ---------------------------------------------------------------------------
__global__ __launch_bounds__(256) void k_chunk(const __bf16* __restrict__ projb,
                                               const float* __restrict__ dtraw,
                                               const float* __restrict__ cw,
                                               const float* __restrict__ cb,
                                               const float* __restrict__ A_log,
                                               const float* __restrict__ dt_bias,
                                               const float* __restrict__ Dv,
                                               float* __restrict__ clog,
                                               __bf16* __restrict__ yssm,
                                               __bf16* __restrict__ Sloc) {
    int blk = blockIdx.x;
    int c  = blk & 31;
    int hh = (blk >> 5) & 31;
    int b  = blk >> 10;
    int tid = threadIdx.x;
    long rowbase = (long)b * L_SEQ + c * QCH;

    __shared__ __align__(16) __bf16 sB[64 * 136];    // B_chunk [s][n]; late: Sloc bounce
    __shared__ __align__(16) __bf16 sU[128 * 72];    // ph1: C [t][n] str136; ph2: B^T [n][s] str72
    __shared__ __align__(16) __bf16 sXT[64 * 72];    // dtx^T [p][s]
    __shared__ __align__(16) __bf16 sXCM[67 * 72];   // ph1: raw x; ph2: M [t][s]; late: y bounce
    __shared__ __align__(16) __bf16 sXCo[64 * 72];   // conv-silu output xc [t][p]
    __shared__ float sCW[256];
    __shared__ float sCB[64];
    __shared__ float sclog[64];
    __shared__ float sdt[64];
    __shared__ float sw[64];

    // ---- stage B, C (bf16 direct) ----
    #pragma unroll
    for (int j = 0; j < 4; j++) {
        int off = j * 256 + tid;          // 1024 bf16x8 = 64 rows * 16
        int t  = off >> 4;
        int n8 = (off & 15) * 8;
        const __bf16* pr = projb + (rowbase + t) * (long)PS;
        *(bf16x8*)&sB[t * 136 + n8] = *(const bf16x8*)(pr + 4096 + n8);
        *(bf16x8*)&sU[t * 136 + n8] = *(const bf16x8*)(pr + 4224 + n8);
    }
    // ---- stage raw x rows ss=0..66 (t = ss-3; zero before seq start) ----
    #pragma unroll
    for (int j = 0; j < 3; j++) {
        int off = j * 256 + tid;          // need 536 = 67 rows * 8 chunks
        if (off < 536) {
            int ss = off >> 3;
            int p8 = (off & 7) * 8;
            bf16x8 xv;
            #pragma unroll
            for (int k = 0; k < 8; k++) xv[k] = (__bf16)0.0f;
            if (c > 0 || ss >= 3)
                xv = *(const bf16x8*)(projb + (rowbase + ss - 3) * (long)PS + DI + hh * HD + p8);
            *(bf16x8*)&sXCM[ss * 72 + p8] = xv;
        }
    }
    sCW[tid] = cw[hh * 256 + tid];
    if (tid < 64) sCB[tid] = cb[hh * 64 + tid];

    // ---- wave 0: dt = softplus (fp32 dtraw), clog = inclusive scan ----
    if (tid < 64) {
        float xr = dtraw[(rowbase + tid) * 32 + hh] + dt_bias[hh];
        float dt = (xr > 20.0f) ? xr : log1pf(expf(xr));
        float la = -expf(A_log[hh]);
        float v = la * dt;
        #pragma unroll
        for (int off = 1; off < 64; off <<= 1) {
            float u = __shfl_up(v, off, 64);
            if (tid >= off) v += u;
        }
        sdt[tid] = dt;
        sclog[tid] = v;
        clog[(rowbase + tid) * NH + hh] = v;
    }
    __syncthreads();

    // ---- conv K=4 + SiLU (vectorized): thread owns fixed p8, two s rows ----
    {
        int p8 = (tid & 7) * 8;
        float wreg[8][4], breg[8];
        #pragma unroll
        for (int e = 0; e < 8; e++) {
            breg[e] = sCB[p8 + e];
            #pragma unroll
            for (int j = 0; j < 4; j++) wreg[e][j] = sCW[(p8 + e) * 4 + j];
        }
        #pragma unroll
        for (int i = 0; i < 2; i++) {
            int s = i * 32 + (tid >> 3);
            bf16x8 r0 = *(const bf16x8*)&sXCM[(s + 0) * 72 + p8];
            bf16x8 r1 = *(const bf16x8*)&sXCM[(s + 1) * 72 + p8];
            bf16x8 r2 = *(const bf16x8*)&sXCM[(s + 2) * 72 + p8];
            bf16x8 r3 = *(const bf16x8*)&sXCM[(s + 3) * 72 + p8];
            float dts = sdt[s];
            bf16x8 oc;
            #pragma unroll
            for (int e = 0; e < 8; e++) {
                float acc = breg[e];
                acc = fmaf(wreg[e][0], (float)r0[e], acc);
                acc = fmaf(wreg[e][1], (float)r1[e], acc);
                acc = fmaf(wreg[e][2], (float)r2[e], acc);
                acc = fmaf(wreg[e][3], (float)r3[e], acc);
                float xc = acc / (1.0f + expf(-acc));
                oc[e] = (__bf16)xc;
                sXT[(p8 + e) * 72 + s] = (__bf16)(dts * xc);
            }
            *(bf16x8*)&sXCo[s * 72 + p8] = oc;
        }
    }
    if (tid < 64) sw[tid] = expf(sclog[63] - sclog[tid]);
    __syncthreads();   // conv reads of sXCM done -> sXCM reusable as sM

    int lane = tid & 63, w = tid >> 6;
    int ln = lane & 15;
    int quad = lane >> 4;
    int kc = quad * 8;

    // ---- G = C @ B^T ----
    bf16x8 caf[4];
    #pragma unroll
    for (int k0 = 0; k0 < 4; k0++)
        caf[k0] = *(const bf16x8*)&sU[(16 * w + ln) * 136 + kc + k0 * 32];
    f32x4 g[4] = {};
    #pragma unroll
    for (int j = 0; j < 4; j++)
        #pragma unroll
        for (int k0 = 0; k0 < 4; k0++) {
            bf16x8 bf_ = *(const bf16x8*)&sB[(16 * j + ln) * 136 + kc + k0 * 32];
            g[j] = __builtin_amdgcn_mfma_f32_16x16x32_bf16(caf[k0], bf_, g[j], 0, 0, 0);
        }

    // ---- M[t,s] = (s<=t) ? exp(clog_t - clog_s) * G : 0 -> sXCM overlay ----
    {
        int trow = 16 * w + quad * 4;
        #pragma unroll
        for (int r = 0; r < 4; r++) {
            int t = trow + r;
            float ct = sclog[t];
            #pragma unroll
            for (int j = 0; j < 4; j++) {
                int s = 16 * j + ln;
                float v = (s <= t) ? g[j][r] * expf(ct - sclog[s]) : 0.0f;
                sXCM[t * 72 + s] = (__bf16)v;
            }
        }
    }
    __syncthreads();   // sM complete; sU (C) now dead

    // ---- transpose sB -> sU as B^T [n][s] (stride 72) ----
    #pragma unroll
    for (int j = 0; j < 4; j++) {
        int s  = tid & 63;
        int n8 = (j * 4 + (tid >> 6)) * 8;
        bf16x8 v = *(const bf16x8*)&sB[s * 136 + n8];
        #pragma unroll
        for (int k = 0; k < 8; k++) sU[(n8 + k) * 72 + s] = v[k];
    }

    // ---- Y = M @ DTX + D[h]*xc  -> band-local sXCM bounce -> bf16x8 store ----
    {
        float Dh = Dv[hh];
        bf16x8 maf[2];
        #pragma unroll
        for (int k0 = 0; k0 < 2; k0++)
            maf[k0] = *(const bf16x8*)&sXCM[(16 * w + ln) * 72 + kc + k0 * 32];
        f32x4 y[4] = {};
        #pragma unroll
        for (int j = 0; j < 4; j++)
            #pragma unroll
            for (int k0 = 0; k0 < 2; k0++) {
                bf16x8 xf = *(const bf16x8*)&sXT[(16 * j + ln) * 72 + kc + k0 * 32];
                y[j] = __builtin_amdgcn_mfma_f32_16x16x32_bf16(maf[k0], xf, y[j], 0, 0, 0);
            }
        // band-local: wave w writes rows 16w..16w+15 only (maf read them first;
        // in-wave LDS ordering covers the WAR). p spans 0..63 (< stride 72).
        #pragma unroll
        for (int j = 0; j < 4; j++)
            #pragma unroll
            for (int r = 0; r < 4; r++) {
                int t = 16 * w + quad * 4 + r;
                int p = 16 * j + ln;
                sXCM[t * 72 + p] = (__bf16)(y[j][r] + Dh * (float)sXCo[t * 72 + p]);
            }
        // vectorized store: 16 rows x 8 chunks = 128 chunks/wave, 2 per lane
        #pragma unroll
        for (int i = 0; i < 2; i++) {
            int idx = lane * 2 + i;
            int r16 = idx >> 3;
            int c8  = (idx & 7) * 8;
            int tt  = 16 * w + r16;
            *(bf16x8*)&yssm[(rowbase + tt) * DI + hh * HD + c8] =
                *(const bf16x8*)&sXCM[tt * 72 + c8];
        }
    }
    __syncthreads();   // sU (B^T) complete; also: all cross-wave sB reads done

    // ---- S_loc[p,n] = sum_s w_s*dtx[s,p]*B[s,n] -> band-local sB bounce ----
    {
        bf16x8 xaf[2];
        #pragma unroll
        for (int k0 = 0; k0 < 2; k0++) {
            bf16x8 raw = *(const bf16x8*)&sXT[(16 * w + ln) * 72 + kc + k0 * 32];
            bf16x8 sc;
            #pragma unroll
            for (int jj = 0; jj < 8; jj++) {
                int s = kc + k0 * 32 + jj;
                sc[jj] = (__bf16)((float)raw[jj] * sw[s]);
            }
            xaf[k0] = sc;
        }
        f32x4 sacc[8] = {};
        #pragma unroll
        for (int j = 0; j < 8; j++)
            #pragma unroll
            for (int k0 = 0; k0 < 2; k0++) {
                bf16x8 btf = *(const bf16x8*)&sU[(16 * j + ln) * 72 + kc + k0 * 32];
                sacc[j] = __builtin_amdgcn_mfma_f32_16x16x32_bf16(xaf[k0], btf, sacc[j], 0, 0, 0);
            }
        // band-local bounce into sB (dead after transpose; barrier above
        // ordered every wave past its sB reads). Rows p in 16w..16w+15.
        #pragma unroll
        for (int j = 0; j < 8; j++)
            #pragma unroll
            for (int r = 0; r < 4; r++) {
                int p = 16 * w + quad * 4 + r;
                int n = 16 * j + ln;
                sB[p * 136 + n] = (__bf16)sacc[j][r];
            }
        long sbase = ((long)(b * NH + hh) * NC + c) * (HD * DS);
        // vectorized store: 16 rows x 16 chunks = 256 chunks/wave, 4 per lane
        #pragma unroll
        for (int i = 0; i < 4; i++) {
            int idx = lane * 4 + i;
            int r16 = idx >> 4;
            int c8  = (idx & 15) * 8;
            int p   = 16 * w + r16;
            *(bf16x8*)&Sloc[sbase + p * DS + c8] = *(const bf16x8*)&sB[p * 136 + c8];
        }
    }
}

// ---------------------------------------------------------------------------
// Fused: carry [blocks 0..1023, bf16x2 per thread] + f2b(Wo) [1024..3071].
// lam table once per block in LDS; serial chain software-pipelined (S[c+1]
// prefetched before the T[c] store).
// ---------------------------------------------------------------------------
__global__ __launch_bounds__(256) void k_carry_f2b(__bf16* __restrict__ Sloc,
                                                   const float* __restrict__ clog,
                                                   const float* __restrict__ Wo,
                                                   __bf16* __restrict__ Wob) {
    int bid = blockIdx.x;
    int tid = threadIdx.x;
    if (bid >= 1024) {
        int i = (bid - 1024) * 256 + tid;    // < (DM*DI)/4
        float4 v = ((const float4*)Wo)[i];
        bf16x4 o = { (__bf16)v.x, (__bf16)v.y, (__bf16)v.z, (__bf16)v.w };
        ((bf16x4*)Wob)[i] = o;
        return;
    }
    int idx = bid * 256 + tid;               // < 262144 (one bf16x2 pair each)
    int n2 = idx & 63;                       // pair index: n = 2*n2, 2*n2+1
    int p  = (idx >> 6) & 63;
    int hh = (idx >> 12) & 31;               // block-uniform
    int b  = idx >> 17;                      // block-uniform

    __shared__ float slam[NC];
    if (tid < NC)
        slam[tid] = expf(clog[((long)b * L_SEQ + tid * QCH + QCH - 1) * NH + hh]);
    __syncthreads();

    long base = ((long)(b * NH + hh) * NC) * (HD * DS) + p * DS + n2 * 2;
    const long cstride = HD * DS;
    float T0 = 0.0f, T1 = 0.0f;
    long a = base;
    bf16x2 Sv = *(const bf16x2*)&Sloc[a];
    for (int c = 0; c < NC; c++) {
        bf16x2 Sn;
        if (c + 1 < NC) Sn = *(const bf16x2*)&Sloc[a + cstride];
        float lam = slam[c];
        bf16x2 Tv = { (__bf16)T0, (__bf16)T1 };
        *(bf16x2*)&Sloc[a] = Tv;
        T0 = fmaf(T0, lam, (float)Sv[0]);
        T1 = fmaf(T1, lam, (float)Sv[1]);
        Sv = Sn;
        a += cstride;
    }
}

// ---------------------------------------------------------------------------
// Phase C + gate (MFMA). NEW (R9): all epilogue traffic vectorized.
//  - z slice staged upfront into sZ (bf16x8 loads).
//  - yb loaded per-wave-band as bf16x8 BEFORE the MFMA burst (latency hides
//    under MFMA, T14 split), parked in sC band (dead after caf; in-wave
//    LDS ordering covers the WAR — caf reads issue first).
//  - output bounced through sH band (barrier after MFMA already required),
//    then stored as bf16x8, 16B/lane coalesced.
// LDS 44.3 KB -> 3 blocks/CU.
// ---------------------------------------------------------------------------
__global__ __launch_bounds__(256, 3) void k_fix(const __bf16* __restrict__ projb,
                                                const __bf16* __restrict__ Sloc,
                                                const float* __restrict__ clog,
                                                const __bf16* __restrict__ yb,
                                                __bf16* __restrict__ yg) {
    int blk = blockIdx.x;
    int c  = blk & 31;
    int hh = (blk >> 5) & 31;
    int b  = blk >> 10;

    __shared__ __align__(16) __bf16 sC[64 * 136];   // C [t][n]; late: yb band park
    __shared__ __align__(16) __bf16 sH[64 * 136];   // Hin [p][n]; late: out bounce
    __shared__ __align__(16) __bf16 sZ[64 * 72];    // z slice [t][p]
    __shared__ float sP[64];

    int tid = threadIdx.x;
    long hbase = ((long)(b * NH + hh) * NC + c) * (HD * DS);
    long rowbase = (long)b * L_SEQ + c * QCH;

    #pragma unroll
    for (int j = 0; j < 4; j++) {
        int off = j * 256 + tid;          // 1024 bf16x8
        int t  = off >> 4;
        int n8 = (off & 15) * 8;
        *(bf16x8*)&sC[t * 136 + n8] =
            *(const bf16x8*)(projb + (rowbase + t) * (long)PS + 4224 + n8);
    }
    #pragma unroll
    for (int j = 0; j < 4; j++) {
        int off = j * 256 + tid;          // 1024 bf16x8 = 64 p-rows * 16
        int p  = off >> 4;
        int n8 = (off & 15) * 8;
        *(bf16x8*)&sH[p * 136 + n8] = *(const bf16x8*)&Sloc[hbase + (long)off * 8];
    }
    #pragma unroll
    for (int j = 0; j < 2; j++) {
        int off = j * 256 + tid;          // 512 bf16x8 = 64 rows * 8 chunks
        int t  = off >> 3;
        int p8 = (off & 7) * 8;
        *(bf16x8*)&sZ[t * 72 + p8] =
            *(const bf16x8*)(projb + (rowbase + t) * (long)PS + hh * HD + p8);
    }
    if (tid < 64) sP[tid] = expf(clog[(rowbase + tid) * NH + hh]);
    __syncthreads();

    int lane = tid & 63, w = tid >> 6;
    int ln = lane & 15;
    int quad = lane >> 4;
    int kc = quad * 8;

    bf16x8 caf[4];
    #pragma unroll
    for (int k0 = 0; k0 < 4; k0++)
        caf[k0] = *(const bf16x8*)&sC[(16 * w + ln) * 136 + kc + k0 * 32];

    // issue band yb loads now — latency hides under the MFMA burst (T14)
    bf16x8 ybr[2];
    #pragma unroll
    for (int i = 0; i < 2; i++) {
        int idx = lane * 2 + i;
        int r16 = idx >> 3;
        int c8  = (idx & 7) * 8;
        ybr[i] = *(const bf16x8*)&yb[(rowbase + 16 * w + r16) * DI + hh * HD + c8];
    }

    f32x4 acc4[4] = {};
    #pragma unroll
    for (int j = 0; j < 4; j++)
        #pragma unroll
        for (int k0 = 0; k0 < 4; k0++) {
            bf16x8 hf = *(const bf16x8*)&sH[(16 * j + ln) * 136 + kc + k0 * 32];
            acc4[j] = __builtin_amdgcn_mfma_f32_16x16x32_bf16(caf[k0], hf, acc4[j], 0, 0, 0);
        }

    // park yb in sC band (caf fragments already read; band-local, in-wave order)
    #pragma unroll
    for (int i = 0; i < 2; i++) {
        int idx = lane * 2 + i;
        int r16 = idx >> 3;
        int c8  = (idx & 7) * 8;
        *(bf16x8*)&sC[(16 * w + r16) * 136 + c8] = ybr[i];
    }
    __syncthreads();   // all cross-wave sH reads done -> sH reusable as out bounce

    #pragma unroll
    for (int j = 0; j < 4; j++)
        #pragma unroll
        for (int r = 0; r < 4; r++) {
            int t = 16 * w + quad * 4 + r;
            int p = 16 * j + ln;
            float pm = sP[t];
            float z  = (float)sZ[t * 72 + p];
            float yv = (float)sC[t * 136 + p];
            float o = (yv + pm * acc4[j][r]) * (z / (1.0f + expf(-z)));
            sH[t * 136 + p] = (__bf16)o;   // band-local bounce
        }
    // vectorized store: 16 rows x 8 chunks = 128 chunks/wave, 2 per lane
    #pragma unroll
    for (int i = 0; i < 2; i++) {
        int idx = lane * 2 + i;
        int r16 = idx >> 3;
        int c8  = (idx & 7) * 8;
        int t   = 16 * w + r16;
        *(bf16x8*)&yg[(rowbase + t) * DI + hh * HD + c8] =
            *(const bf16x8*)&sH[t * 136 + c8];
    }
}

// ---------------------------------------------------------------------------
extern "C" void kernel_launch(void* const* d_in, const int* in_sizes, int n_in,
                              void* d_out, int out_size, void* d_ws, size_t ws_size,
                              hipStream_t stream) {
    const float* x       = (const float*)d_in[0];
    const float* norm_w  = (const float*)d_in[1];
    const float* Wp      = (const float*)d_in[2];   // (4384, 1024)
    const float* cw      = (const float*)d_in[3];
    const float* cb      = (const float*)d_in[4];
    const float* A_log   = (const float*)d_in[5];
    const float* Dv      = (const float*)d_in[6];
    const float* dt_bias = (const float*)d_in[7];
    const float* Wo      = (const float*)d_in[8];   // (1024, 2048)
    float* out = (float*)d_out;

    // workspace (float units):
    float* ws     = (float*)d_ws;
    __bf16* projb = (__bf16*)ws;              //  9,175,040 fl (18,350,080 bf16)
    float* dtraw  = ws    + 9175040;          //    131,072
    float* clog   = dtraw + 131072;           //    131,072
    float* ybh    = clog  + 131072;           //  4,194,304 fl (yb bf16)
    float* ybf    = ybh   + 4194304;          //  4,194,304 fl (ybb bf16)
    float* wob_s  = ybf   + 4194304;          //  1,048,576 fl (Wob bf16)
    float* U      = wob_s + 1048576;          // 16,777,216 (Sloc bf16 uses half)
    // total 35,651,584 floats = 142.6 MB

    __bf16* xnb  = (__bf16*)U;
    __bf16* Wpb  = (__bf16*)(U + 2097152);
    __bf16* Sloc = (__bf16*)U;                // 33,554,432 bf16 fits the slot
    __bf16* Wob  = (__bf16*)wob_s;
    __bf16* ybb  = (__bf16*)ybf;
    __bf16* yb   = (__bf16*)ybh;

    // phase 1: f2b(Wp) + rmsnorm fused, then in_proj GEMM (proven 128²)
    k_prep<<<4384 + M_ROWS, 256, 0, stream>>>(Wp, Wpb, x, norm_w, xnb);
    {
        dim3 g(PS / 128, M_ROWS / 128);
        k_gemm_bf<<<g, 256, 0, stream>>>(xnb, Wpb, projb, dtraw, DP, DM, PS);
    }

    // phase 2: chunked scan (Sloc overwrites xnb/Wpb — dead)
    k_chunk<<<B_SZ * NH * NC, 256, 0, stream>>>(projb, dtraw, cw, cb, A_log,
                                                dt_bias, Dv, clog, yb, Sloc);
    k_carry_f2b<<<3072, 256, 0, stream>>>(Sloc, clog, Wo, Wob);
    k_fix<<<B_SZ * NH * NC, 256, 0, stream>>>(projb, Sloc, clog, yb, ybb);

    // phase 3: out_proj (BM=64 tile -> 512 blocks, 2+/CU, counted sched)
    {
        dim3 g(DM / 128, M_ROWS / 64);
        k_gemm_out<<<g, 256, 0, stream>>>(ybb, Wob, x, out, DI, DM);
    }
}

// Round 10
// 257.067 us; speedup vs baseline: 1.0424x; 1.0424x over previous
//
#include <hip/hip_runtime.h>
#include <math.h>

#define B_SZ     2
#define L_SEQ    2048
#define DM       1024      // D_MODEL
#define DP       4384      // D_PROJ (logical)
#define PS       4480      // proj padded stride (35 * 128)
#define DI       2048      // D_INNER
#define NH       32        // N_HEADS
#define HD       64        // HEAD_DIM
#define DS       128       // D_STATE
#define M_ROWS   (B_SZ * L_SEQ)   // 4096
#define QCH      64        // scan chunk length
#define NC       (L_SEQ / QCH)    // 32 chunks

typedef __bf16 bf16x8 __attribute__((ext_vector_type(8)));
typedef __bf16 bf16x4 __attribute__((ext_vector_type(4)));
typedef __bf16 bf16x2 __attribute__((ext_vector_type(2)));
typedef float  f32x4  __attribute__((ext_vector_type(4)));

// async global->LDS, 16B per lane. LDS dest is wave-uniform base + lane*16.
__device__ __forceinline__ void gload16(const void* g, void* l) {
    __builtin_amdgcn_global_load_lds(
        (const __attribute__((address_space(1))) unsigned int*)g,
        (__attribute__((address_space(3))) unsigned int*)l,
        16, 0, 0);
}

// ---------------------------------------------------------------------------
// Fused: f2b(Wp) [blocks 0..4383] + RMSNorm [blocks 4384..8479]
// ---------------------------------------------------------------------------
__global__ __launch_bounds__(256) void k_prep(const float* __restrict__ Wp,
                                              __bf16* __restrict__ Wpb,
                                              const float* __restrict__ x,
                                              const float* __restrict__ w,
                                              __bf16* __restrict__ xn) {
    int tid = threadIdx.x;
    if (blockIdx.x < 4384) {
        int i = blockIdx.x * 256 + tid;          // < (DP*DM)/4
        float4 v = ((const float4*)Wp)[i];
        bf16x4 o = { (__bf16)v.x, (__bf16)v.y, (__bf16)v.z, (__bf16)v.w };
        ((bf16x4*)Wpb)[i] = o;
        return;
    }
    int row = blockIdx.x - 4384;
    const float4* x4 = (const float4*)(x + (long)row * DM);
    float4 v = x4[tid];
    float ss = v.x * v.x + v.y * v.y + v.z * v.z + v.w * v.w;
    #pragma unroll
    for (int off = 32; off > 0; off >>= 1) ss += __shfl_xor(ss, off, 64);
    __shared__ float sred[4];
    if ((tid & 63) == 0) sred[tid >> 6] = ss;
    __syncthreads();
    float tot = sred[0] + sred[1] + sred[2] + sred[3];
    float scale = rsqrtf(tot * (1.0f / (float)DM) + 1e-6f);
    const float4* w4 = (const float4*)w;
    float4 wv = w4[tid];
    bf16x4 o = { (__bf16)(v.x * scale * wv.x), (__bf16)(v.y * scale * wv.y),
                 (__bf16)(v.z * scale * wv.z), (__bf16)(v.w * scale * wv.w) };
    ((bf16x4*)(xn + (long)row * DM))[tid] = o;
}

// ---------------------------------------------------------------------------
// in_proj GEMM (PROVEN schedule — 63-76us across sessions, ~600 TF family
// ceiling): 128x128 tile, BK=64, double-buffered global_load_lds,
// source-XOR swizzle -> 0 bank conflicts, counted-vmcnt schedule.
// NEW (R10): 2D-cluster XCD swizzle — each XCD (orig%8) walks 7 supertiles
// of 5bx x 4by (20 blocks); L2 working set = 5 B-panels + 4 A-panels
// (2.25 MB < 4 MB per-XCD L2) vs old 1D scheme's all-35-B-panels thrash.
// Bijective: (sy,k) <-> (bx,by) by construction for the 35x32 grid.
// ---------------------------------------------------------------------------
__global__ __launch_bounds__(256) void k_gemm_bf(const __bf16* __restrict__ A,
                                                 const __bf16* __restrict__ W,
                                                 __bf16* __restrict__ Cb,
                                                 float* __restrict__ Dt,
                                                 int Nw, int K, int ldc) {
    __shared__ __align__(16) __bf16 As[2][128 * 64];
    __shared__ __align__(16) __bf16 Bs[2][128 * 64];
    int t = threadIdx.x;

    int gx = gridDim.x;
    int nwg = gx * gridDim.y;
    int orig = blockIdx.y * gx + blockIdx.x;
    int bx, by;
    if (gx == 35 && gridDim.y == 32) {
        int sy = orig & 7;          // XCD id
        int k  = orig >> 3;         // 0..139
        int st = k / 20;            // supertile column 0..6
        int wv = k % 20;            // position in 5x4 supertile
        bx = st * 5 + wv % 5;
        by = sy * 4 + wv / 5;
    } else {
        int wgid = (nwg & 7) ? orig : ((orig & 7) * (nwg >> 3) + (orig >> 3));
        bx = wgid % gx; by = wgid / gx;
    }
    int bm = by * 128, bn = bx * 128;

    int lane = t & 63, w = t >> 6;

    int rl = lane >> 3;                  // row-in-8 (== row & 7 of target row)
    int lc = (lane & 7) ^ rl;            // pre-swizzled source logical chunk
    int rbase = w * 32 + rl;
    const __bf16* Agp[4];
    const __bf16* Wgp[4];
    #pragma unroll
    for (int i = 0; i < 4; i++) {
        Agp[i] = A + (long)(bm + rbase + i * 8) * K + lc * 8;
        int rb = bn + rbase + i * 8; if (rb >= Nw) rb = Nw - 1;
        Wgp[i] = W + (long)rb * K + lc * 8;
    }

    int wm = (w & 1) * 64, wn = (w >> 1) * 64;
    int ln = lane & 15;
    int q  = lane >> 4;

    f32x4 acc[4][4] = {};

    int nst = K >> 6;

    #pragma unroll
    for (int i = 0; i < 4; i++) {
        gload16(Agp[i], As[0] + (w * 4 + i) * 512);
        gload16(Wgp[i], Bs[0] + (w * 4 + i) * 512);
    }

    int cur = 0;
    for (int s = 0; s < nst; ++s) {
        if (s + 1 < nst) {
            long k1 = (long)(s + 1) << 6;
            #pragma unroll
            for (int i = 0; i < 4; i++) {
                gload16(Agp[i] + k1, As[cur ^ 1] + (w * 4 + i) * 512);
                gload16(Wgp[i] + k1, Bs[cur ^ 1] + (w * 4 + i) * 512);
            }
            asm volatile("s_waitcnt vmcnt(8)" ::: "memory");  // s done; s+1 in flight
        } else {
            asm volatile("s_waitcnt vmcnt(0)" ::: "memory");  // final tile: drain
        }
        __builtin_amdgcn_sched_barrier(0);
        __builtin_amdgcn_s_barrier();        // tile s visible to all waves
        __builtin_amdgcn_sched_barrier(0);
        __builtin_amdgcn_s_setprio(1);

        const __bf16* Asc = As[cur];
        const __bf16* Bsc = Bs[cur];
        #pragma unroll
        for (int h = 0; h < 2; h++) {
            int ch = (4 * h + q);
            int koff = ((ch ^ (ln & 7)) << 3);   // (R&7)==(ln&7): wm,i*16 ≡ 0 mod 8
            bf16x8 af[4], bfr[4];
            #pragma unroll
            for (int i = 0; i < 4; i++)
                af[i]  = *(const bf16x8*)(Asc + (wm + ln + i * 16) * 64 + koff);
            #pragma unroll
            for (int j = 0; j < 4; j++)
                bfr[j] = *(const bf16x8*)(Bsc + (wn + ln + j * 16) * 64 + koff);
            #pragma unroll
            for (int i = 0; i < 4; i++)
                #pragma unroll
                for (int j = 0; j < 4; j++)
                    acc[i][j] = __builtin_amdgcn_mfma_f32_16x16x32_bf16(
                                    af[i], bfr[j], acc[i][j], 0, 0, 0);
        }
        __builtin_amdgcn_s_setprio(0);
        __builtin_amdgcn_sched_barrier(0);
        __builtin_amdgcn_s_barrier();        // reads done before buf reuse
        __builtin_amdgcn_sched_barrier(0);
        cur ^= 1;
    }

    int colbase = bn + wn + ln;
    #pragma unroll
    for (int i = 0; i < 4; i++) {
        #pragma unroll
        for (int r = 0; r < 4; r++) {
            int m = bm + wm + i * 16 + (lane >> 4) * 4 + r;
            long off = (long)m * ldc + colbase;
            #pragma unroll
            for (int j = 0; j < 4; j++) {
                float v = acc[i][j][r];
                Cb[off + j * 16] = (__bf16)v;
                int col = colbase + j * 16;
                if (col >= 4352 && col < 4384)
                    Dt[(long)m * 32 + (col - 4352)] = v;
            }
        }
    }
}

// ---------------------------------------------------------------------------
// out_proj GEMM: BM=64 x BN=128 tile, BK=64 -> 512 blocks (2/CU), counted
// vmcnt(6). NEW (R10): 2D-cluster XCD swizzle (2bx x 4by supertiles of 8):
// working set 2 B-panels + 4 A-panels = 2 MB < 4 MB L2. Bijective for 8x64.
// ---------------------------------------------------------------------------
__global__ __launch_bounds__(256) void k_gemm_out(const __bf16* __restrict__ A,
                                                  const __bf16* __restrict__ W,
                                                  const float* __restrict__ resid,
                                                  float* __restrict__ Cf,
                                                  int K, int ldc) {
    __shared__ __align__(16) __bf16 As[2][64 * 64];
    __shared__ __align__(16) __bf16 Bs[2][128 * 64];
    int t = threadIdx.x;

    int gx = gridDim.x;                      // 8
    int nwg = gx * gridDim.y;                // 512
    int orig = blockIdx.y * gx + blockIdx.x;
    int bx, by;
    if (gx == 8 && gridDim.y == 64) {
        int xcd = orig & 7;
        int k   = orig >> 3;                 // 0..63
        int st  = k >> 3;                    // supertile 0..7
        int wv  = k & 7;                     // position in 2x4 supertile
        bx = (st & 3) * 2 + (wv & 1);
        by = xcd * 8 + (st >> 2) * 4 + (wv >> 1);
    } else {
        int wgid = (nwg & 7) ? orig : ((orig & 7) * (nwg >> 3) + (orig >> 3));
        bx = wgid % gx; by = wgid / gx;
    }
    int bm = by * 64, bn = bx * 128;

    int lane = t & 63, w = t >> 6;

    int rl = lane >> 3;
    int lc = (lane & 7) ^ rl;                // pre-swizzled source chunk
    const __bf16* Agp[2];
    const __bf16* Wgp[4];
    #pragma unroll
    for (int i = 0; i < 2; i++)
        Agp[i] = A + (long)(bm + w * 16 + i * 8 + rl) * K + lc * 8;
    #pragma unroll
    for (int i = 0; i < 4; i++)
        Wgp[i] = W + (long)(bn + w * 32 + i * 8 + rl) * K + lc * 8;

    int wm = (w & 1) * 32, wn = (w >> 1) * 64;
    int ln = lane & 15;
    int q  = lane >> 4;

    f32x4 acc[2][4] = {};

    int nst = K >> 6;                        // 32

    #pragma unroll
    for (int i = 0; i < 2; i++) gload16(Agp[i], As[0] + (w * 2 + i) * 512);
    #pragma unroll
    for (int i = 0; i < 4; i++) gload16(Wgp[i], Bs[0] + (w * 4 + i) * 512);

    int cur = 0;
    for (int s = 0; s < nst; ++s) {
        if (s + 1 < nst) {
            long k1 = (long)(s + 1) << 6;
            #pragma unroll
            for (int i = 0; i < 2; i++)
                gload16(Agp[i] + k1, As[cur ^ 1] + (w * 2 + i) * 512);
            #pragma unroll
            for (int i = 0; i < 4; i++)
                gload16(Wgp[i] + k1, Bs[cur ^ 1] + (w * 4 + i) * 512);
            asm volatile("s_waitcnt vmcnt(6)" ::: "memory");
        } else {
            asm volatile("s_waitcnt vmcnt(0)" ::: "memory");
        }
        __builtin_amdgcn_sched_barrier(0);
        __builtin_amdgcn_s_barrier();
        __builtin_amdgcn_sched_barrier(0);
        __builtin_amdgcn_s_setprio(1);

        const __bf16* Asc = As[cur];
        const __bf16* Bsc = Bs[cur];
        #pragma unroll
        for (int h = 0; h < 2; h++) {
            int ch = (4 * h + q);
            int koff = ((ch ^ (ln & 7)) << 3);
            bf16x8 af[2], bfr[4];
            #pragma unroll
            for (int i = 0; i < 2; i++)
                af[i]  = *(const bf16x8*)(Asc + (wm + ln + i * 16) * 64 + koff);
            #pragma unroll
            for (int j = 0; j < 4; j++)
                bfr[j] = *(const bf16x8*)(Bsc + (wn + ln + j * 16) * 64 + koff);
            #pragma unroll
            for (int i = 0; i < 2; i++)
                #pragma unroll
                for (int j = 0; j < 4; j++)
                    acc[i][j] = __builtin_amdgcn_mfma_f32_16x16x32_bf16(
                                    af[i], bfr[j], acc[i][j], 0, 0, 0);
        }
        __builtin_amdgcn_s_setprio(0);
        __builtin_amdgcn_sched_barrier(0);
        __builtin_amdgcn_s_barrier();
        __builtin_amdgcn_sched_barrier(0);
        cur ^= 1;
    }

    int colbase = bn + wn + ln;
    #pragma unroll
    for (int i = 0; i < 2; i++) {
        #pragma unroll
        for (int r = 0; r < 4; r++) {
            int m = bm + wm + i * 16 + (lane >> 4) * 4 + r;
            long off = (long)m * ldc + colbase;
            #pragma unroll
            for (int j = 0; j < 4; j++) {
                float v = acc[i][j][r] + resid[off + j * 16];
                Cf[off + j * 16] = v;
            }
        }
    }
}

// ---------------------------------------------------------------------------
// Phase A (MFMA) fused conv+SiLU+dt/cumlog+D-term. NEW (R10): B/C staging via
// global_load_lds (async, no VGPR round-trip). sB/sU phase-1 layout is
// [64][128] LINEAR with phys_chunk = logical ^ (row&7) (source-XOR pattern,
// proven in the GEMMs): reads apply the same XOR -> <=2-way bank access
// (free). The existing __syncthreads drains vmcnt(0) before any read.
// Epilogues: R8 scalar form (R9's LDS-bounce variant measured +6us — reverted).
// ---------------------------------------------------------------------------
__global__ __launch_bounds__(256) void k_chunk(const __bf16* __restrict__ projb,
                                               const float* __restrict__ dtraw,
                                               const float* __restrict__ cw,
                                               const float* __restrict__ cb,
                                               const float* __restrict__ A_log,
                                               const float* __restrict__ dt_bias,
                                               const float* __restrict__ Dv,
                                               float* __restrict__ clog,
                                               __bf16* __restrict__ yssm,
                                               __bf16* __restrict__ Sloc) {
    int blk = blockIdx.x;
    int c  = blk & 31;
    int hh = (blk >> 5) & 31;
    int b  = blk >> 10;
    int tid = threadIdx.x;
    long rowbase = (long)b * L_SEQ + c * QCH;

    __shared__ __align__(16) __bf16 sB[64 * 128];    // B_chunk [s][128] linear-XOR
    __shared__ __align__(16) __bf16 sU[128 * 72];    // ph1: C [t][128] linear-XOR (first 8192); ph2: B^T [n][s] str72
    __shared__ __align__(16) __bf16 sXT[64 * 72];    // dtx^T [p][s]
    __shared__ __align__(16) __bf16 sXCM[67 * 72];   // ph1: raw x [ss][p]; ph2 overlay: M [t][s]
    __shared__ __align__(16) __bf16 sXCo[64 * 72];   // conv-silu output xc [t][p]
    __shared__ float sCW[256];
    __shared__ float sCB[64];
    __shared__ float sclog[64];
    __shared__ float sdt[64];
    __shared__ float sw[64];

    int lane = tid & 63, w = tid >> 6;

    // ---- stage B, C via gload16: wave w, call r stages rows r*16+w*4..+3;
    //      lane l -> row l>>4 (of 4), phys chunk l&15, src logical = phys^(row&7)
    {
        int rl4 = lane >> 4;
        int pc  = lane & 15;
        #pragma unroll
        for (int r = 0; r < 4; r++) {
            int row0 = r * 16 + w * 4;
            int row  = row0 + rl4;
            int lc2  = (pc ^ (row & 7)) * 8;
            const __bf16* pr = projb + (rowbase + row) * (long)PS;
            gload16(pr + 4096 + lc2, sB + row0 * 128);
            gload16(pr + 4224 + lc2, sU + row0 * 128);
        }
    }
    // ---- stage raw x rows ss=0..66 (t = ss-3; zero before seq start) ----
    #pragma unroll
    for (int j = 0; j < 3; j++) {
        int off = j * 256 + tid;          // need 536 = 67 rows * 8 chunks
        if (off < 536) {
            int ss = off >> 3;
            int p8 = (off & 7) * 8;
            bf16x8 xv;
            #pragma unroll
            for (int k = 0; k < 8; k++) xv[k] = (__bf16)0.0f;
            if (c > 0 || ss >= 3)
                xv = *(const bf16x8*)(projb + (rowbase + ss - 3) * (long)PS + DI + hh * HD + p8);
            *(bf16x8*)&sXCM[ss * 72 + p8] = xv;
        }
    }
    sCW[tid] = cw[hh * 256 + tid];
    if (tid < 64) sCB[tid] = cb[hh * 64 + tid];

    // ---- wave 0: dt = softplus (fp32 dtraw), clog = inclusive scan ----
    if (tid < 64) {
        float xr = dtraw[(rowbase + tid) * 32 + hh] + dt_bias[hh];
        float dt = (xr > 20.0f) ? xr : log1pf(expf(xr));
        float la = -expf(A_log[hh]);
        float v = la * dt;
        #pragma unroll
        for (int off = 1; off < 64; off <<= 1) {
            float u = __shfl_up(v, off, 64);
            if (tid >= off) v += u;
        }
        sdt[tid] = dt;
        sclog[tid] = v;
        clog[(rowbase + tid) * NH + hh] = v;
    }
    __syncthreads();   // drains vmcnt(0): sB/sU staged; scan/conv inputs ready

    // ---- conv K=4 + SiLU (vectorized): thread owns fixed p8, two s rows ----
    {
        int p8 = (tid & 7) * 8;
        float wreg[8][4], breg[8];
        #pragma unroll
        for (int e = 0; e < 8; e++) {
            breg[e] = sCB[p8 + e];
            #pragma unroll
            for (int j = 0; j < 4; j++) wreg[e][j] = sCW[(p8 + e) * 4 + j];
        }
        #pragma unroll
        for (int i = 0; i < 2; i++) {
            int s = i * 32 + (tid >> 3);
            bf16x8 r0 = *(const bf16x8*)&sXCM[(s + 0) * 72 + p8];
            bf16x8 r1 = *(const bf16x8*)&sXCM[(s + 1) * 72 + p8];
            bf16x8 r2 = *(const bf16x8*)&sXCM[(s + 2) * 72 + p8];
            bf16x8 r3 = *(const bf16x8*)&sXCM[(s + 3) * 72 + p8];
            float dts = sdt[s];
            bf16x8 oc;
            #pragma unroll
            for (int e = 0; e < 8; e++) {
                float acc = breg[e];
                acc = fmaf(wreg[e][0], (float)r0[e], acc);
                acc = fmaf(wreg[e][1], (float)r1[e], acc);
                acc = fmaf(wreg[e][2], (float)r2[e], acc);
                acc = fmaf(wreg[e][3], (float)r3[e], acc);
                float xc = acc / (1.0f + expf(-acc));
                oc[e] = (__bf16)xc;
                sXT[(p8 + e) * 72 + s] = (__bf16)(dts * xc);
            }
            *(bf16x8*)&sXCo[s * 72 + p8] = oc;
        }
    }
    if (tid < 64) sw[tid] = expf(sclog[63] - sclog[tid]);
    __syncthreads();   // conv reads of sXCM done -> sXCM reusable as sM

    int ln = lane & 15;
    int quad = lane >> 4;
    int kc = quad * 8;

    // ---- G = C @ B^T  (linear-XOR reads: chunk = quad + 4*k0, ^ (ln&7)) ----
    bf16x8 caf[4];
    #pragma unroll
    for (int k0 = 0; k0 < 4; k0++)
        caf[k0] = *(const bf16x8*)&sU[(16 * w + ln) * 128 + (((quad + 4 * k0) ^ (ln & 7)) << 3)];
    f32x4 g[4] = {};
    #pragma unroll
    for (int j = 0; j < 4; j++)
        #pragma unroll
        for (int k0 = 0; k0 < 4; k0++) {
            bf16x8 bf_ = *(const bf16x8*)&sB[(16 * j + ln) * 128 + (((quad + 4 * k0) ^ (ln & 7)) << 3)];
            g[j] = __builtin_amdgcn_mfma_f32_16x16x32_bf16(caf[k0], bf_, g[j], 0, 0, 0);
        }

    // ---- M[t,s] = (s<=t) ? exp(clog_t - clog_s) * G : 0 -> sXCM overlay ----
    {
        int trow = 16 * w + quad * 4;
        #pragma unroll
        for (int r = 0; r < 4; r++) {
            int t = trow + r;
            float ct = sclog[t];
            #pragma unroll
            for (int j = 0; j < 4; j++) {
                int s = 16 * j + ln;
                float v = (s <= t) ? g[j][r] * expf(ct - sclog[s]) : 0.0f;
                sXCM[t * 72 + s] = (__bf16)v;
            }
        }
    }
    __syncthreads();   // sM complete; sU (C) now dead

    // ---- transpose sB -> sU as B^T [n][s] (stride 72); XOR source chunk ----
    #pragma unroll
    for (int j = 0; j < 4; j++) {
        int s  = tid & 63;
        int ch = j * 4 + (tid >> 6);
        bf16x8 v = *(const bf16x8*)&sB[s * 128 + ((ch ^ (s & 7)) << 3)];
        int n8 = ch * 8;
        #pragma unroll
        for (int k = 0; k < 8; k++) sU[(n8 + k) * 72 + s] = v[k];
    }

    // ---- Y = M @ DTX + D[h]*xc  (bf16 out) ----
    {
        float Dh = Dv[hh];
        bf16x8 maf[2];
        #pragma unroll
        for (int k0 = 0; k0 < 2; k0++)
            maf[k0] = *(const bf16x8*)&sXCM[(16 * w + ln) * 72 + kc + k0 * 32];
        f32x4 y[4] = {};
        #pragma unroll
        for (int j = 0; j < 4; j++)
            #pragma unroll
            for (int k0 = 0; k0 < 2; k0++) {
                bf16x8 xf = *(const bf16x8*)&sXT[(16 * j + ln) * 72 + kc + k0 * 32];
                y[j] = __builtin_amdgcn_mfma_f32_16x16x32_bf16(maf[k0], xf, y[j], 0, 0, 0);
            }
        #pragma unroll
        for (int j = 0; j < 4; j++)
            #pragma unroll
            for (int r = 0; r < 4; r++) {
                int t = 16 * w + quad * 4 + r;
                int p = 16 * j + ln;
                float v = y[j][r] + Dh * (float)sXCo[t * 72 + p];
                yssm[(rowbase + t) * DI + hh * HD + p] = (__bf16)v;
            }
    }
    __syncthreads();   // sU (B^T) complete

    // ---- S_loc[p,n] = sum_s w_s * dtx[s,p] * B[s,n]  (bf16 out) ----
    {
        bf16x8 xaf[2];
        #pragma unroll
        for (int k0 = 0; k0 < 2; k0++) {
            bf16x8 raw = *(const bf16x8*)&sXT[(16 * w + ln) * 72 + kc + k0 * 32];
            bf16x8 sc;
            #pragma unroll
            for (int jj = 0; jj < 8; jj++) {
                int s = kc + k0 * 32 + jj;
                sc[jj] = (__bf16)((float)raw[jj] * sw[s]);
            }
            xaf[k0] = sc;
        }
        f32x4 sacc[8] = {};
        #pragma unroll
        for (int j = 0; j < 8; j++)
            #pragma unroll
            for (int k0 = 0; k0 < 2; k0++) {
                bf16x8 btf = *(const bf16x8*)&sU[(16 * j + ln) * 72 + kc + k0 * 32];
                sacc[j] = __builtin_amdgcn_mfma_f32_16x16x32_bf16(xaf[k0], btf, sacc[j], 0, 0, 0);
            }
        long sbase = ((long)(b * NH + hh) * NC + c) * (HD * DS);
        #pragma unroll
        for (int j = 0; j < 8; j++)
            #pragma unroll
            for (int r = 0; r < 4; r++) {
                int p = 16 * w + quad * 4 + r;
                int n = 16 * j + ln;
                Sloc[sbase + p * DS + n] = (__bf16)sacc[j][r];
            }
    }
}

// ---------------------------------------------------------------------------
// Fused: carry [blocks 0..1023, bf16x2 per thread] + f2b(Wo) [1024..3071].
// lam table once per block in LDS; serial chain software-pipelined.
// ---------------------------------------------------------------------------
__global__ __launch_bounds__(256) void k_carry_f2b(__bf16* __restrict__ Sloc,
                                                   const float* __restrict__ clog,
                                                   const float* __restrict__ Wo,
                                                   __bf16* __restrict__ Wob) {
    int bid = blockIdx.x;
    int tid = threadIdx.x;
    if (bid >= 1024) {
        int i = (bid - 1024) * 256 + tid;    // < (DM*DI)/4
        float4 v = ((const float4*)Wo)[i];
        bf16x4 o = { (__bf16)v.x, (__bf16)v.y, (__bf16)v.z, (__bf16)v.w };
        ((bf16x4*)Wob)[i] = o;
        return;
    }
    int idx = bid * 256 + tid;               // < 262144 (one bf16x2 pair each)
    int n2 = idx & 63;                       // pair index: n = 2*n2, 2*n2+1
    int p  = (idx >> 6) & 63;
    int hh = (idx >> 12) & 31;               // block-uniform
    int b  = idx >> 17;                      // block-uniform

    __shared__ float slam[NC];
    if (tid < NC)
        slam[tid] = expf(clog[((long)b * L_SEQ + tid * QCH + QCH - 1) * NH + hh]);
    __syncthreads();

    long base = ((long)(b * NH + hh) * NC) * (HD * DS) + p * DS + n2 * 2;
    const long cstride = HD * DS;
    float T0 = 0.0f, T1 = 0.0f;
    long a = base;
    bf16x2 Sv = *(const bf16x2*)&Sloc[a];
    for (int c = 0; c < NC; c++) {
        bf16x2 Sn;
        if (c + 1 < NC) Sn = *(const bf16x2*)&Sloc[a + cstride];
        float lam = slam[c];
        bf16x2 Tv = { (__bf16)T0, (__bf16)T1 };
        *(bf16x2*)&Sloc[a] = Tv;
        T0 = fmaf(T0, lam, (float)Sv[0]);
        T1 = fmaf(T1, lam, (float)Sv[1]);
        Sv = Sn;
        a += cstride;
    }
}

// ---------------------------------------------------------------------------
// Phase C + gate (MFMA): Ycorr = C_chunk @ Hin^T, then
// yg = (yb + exp(clog_t)*Ycorr) * silu(z), bf16 out. R8 form (bounce variant
// measured +6us in R9 — reverted). launch_bounds(256,4): ~35KB LDS.
// ---------------------------------------------------------------------------
__global__ __launch_bounds__(256, 4) void k_fix(const __bf16* __restrict__ projb,
                                                const __bf16* __restrict__ Sloc,
                                                const float* __restrict__ clog,
                                                const __bf16* __restrict__ yb,
                                                __bf16* __restrict__ yg) {
    int blk = blockIdx.x;
    int c  = blk & 31;
    int hh = (blk >> 5) & 31;
    int b  = blk >> 10;

    __shared__ __align__(16) __bf16 sC[64 * 136];   // C [t][n]
    __shared__ __align__(16) __bf16 sH[64 * 136];   // Hin [p][n]
    __shared__ float sP[64];

    int tid = threadIdx.x;
    long hbase = ((long)(b * NH + hh) * NC + c) * (HD * DS);
    long rowbase = (long)b * L_SEQ + c * QCH;

    #pragma unroll
    for (int j = 0; j < 4; j++) {
        int off = j * 256 + tid;          // 1024 bf16x8
        int t  = off >> 4;
        int n8 = (off & 15) * 8;
        *(bf16x8*)&sC[t * 136 + n8] =
            *(const bf16x8*)(projb + (rowbase + t) * (long)PS + 4224 + n8);
    }
    #pragma unroll
    for (int j = 0; j < 4; j++) {
        int off = j * 256 + tid;          // 1024 bf16x8 = 64 p-rows * 16
        int p  = off >> 4;
        int n8 = (off & 15) * 8;
        *(bf16x8*)&sH[p * 136 + n8] = *(const bf16x8*)&Sloc[hbase + (long)off * 8];
    }
    if (tid < 64) sP[tid] = expf(clog[(rowbase + tid) * NH + hh]);
    __syncthreads();

    int lane = tid & 63, w = tid >> 6;
    int ln = lane & 15;
    int quad = lane >> 4;
    int kc = quad * 8;

    bf16x8 caf[4];
    #pragma unroll
    for (int k0 = 0; k0 < 4; k0++)
        caf[k0] = *(const bf16x8*)&sC[(16 * w + ln) * 136 + kc + k0 * 32];
    f32x4 acc4[4] = {};
    #pragma unroll
    for (int j = 0; j < 4; j++)
        #pragma unroll
        for (int k0 = 0; k0 < 4; k0++) {
            bf16x8 hf = *(const bf16x8*)&sH[(16 * j + ln) * 136 + kc + k0 * 32];
            acc4[j] = __builtin_amdgcn_mfma_f32_16x16x32_bf16(caf[k0], hf, acc4[j], 0, 0, 0);
        }

    #pragma unroll
    for (int j = 0; j < 4; j++)
        #pragma unroll
        for (int r = 0; r < 4; r++) {
            int t = 16 * w + quad * 4 + r;
            int p = 16 * j + ln;
            long row = rowbase + t;
            long yoff = row * DI + hh * HD + p;
            float pm = sP[t];
            float z = (float)projb[row * (long)PS + hh * HD + p];
            float o = ((float)yb[yoff] + pm * acc4[j][r]) * (z / (1.0f + expf(-z)));
            yg[yoff] = (__bf16)o;
        }
}

// ---------------------------------------------------------------------------
extern "C" void kernel_launch(void* const* d_in, const int* in_sizes, int n_in,
                              void* d_out, int out_size, void* d_ws, size_t ws_size,
                              hipStream_t stream) {
    const float* x       = (const float*)d_in[0];
    const float* norm_w  = (const float*)d_in[1];
    const float* Wp      = (const float*)d_in[2];   // (4384, 1024)
    const float* cw      = (const float*)d_in[3];
    const float* cb      = (const float*)d_in[4];
    const float* A_log   = (const float*)d_in[5];
    const float* Dv      = (const float*)d_in[6];
    const float* dt_bias = (const float*)d_in[7];
    const float* Wo      = (const float*)d_in[8];   // (1024, 2048)
    float* out = (float*)d_out;

    // workspace (float units):
    float* ws     = (float*)d_ws;
    __bf16* projb = (__bf16*)ws;              //  9,175,040 fl (18,350,080 bf16)
    float* dtraw  = ws    + 9175040;          //    131,072
    float* clog   = dtraw + 131072;           //    131,072
    float* ybh    = clog  + 131072;           //  4,194,304 fl (yb bf16)
    float* ybf    = ybh   + 4194304;          //  4,194,304 fl (ybb bf16)
    float* wob_s  = ybf   + 4194304;          //  1,048,576 fl (Wob bf16)
    float* U      = wob_s + 1048576;          // 16,777,216 (Sloc bf16 uses half)
    // total 35,651,584 floats = 142.6 MB

    __bf16* xnb  = (__bf16*)U;
    __bf16* Wpb  = (__bf16*)(U + 2097152);
    __bf16* Sloc = (__bf16*)U;                // 33,554,432 bf16 fits the slot
    __bf16* Wob  = (__bf16*)wob_s;
    __bf16* ybb  = (__bf16*)ybf;
    __bf16* yb   = (__bf16*)ybh;

    // phase 1: f2b(Wp) + rmsnorm fused, then in_proj GEMM (proven 128²)
    k_prep<<<4384 + M_ROWS, 256, 0, stream>>>(Wp, Wpb, x, norm_w, xnb);
    {
        dim3 g(PS / 128, M_ROWS / 128);       // 35 x 32
        k_gemm_bf<<<g, 256, 0, stream>>>(xnb, Wpb, projb, dtraw, DP, DM, PS);
    }

    // phase 2: chunked scan (Sloc overwrites xnb/Wpb — dead)
    k_chunk<<<B_SZ * NH * NC, 256, 0, stream>>>(projb, dtraw, cw, cb, A_log,
                                                dt_bias, Dv, clog, yb, Sloc);
    k_carry_f2b<<<3072, 256, 0, stream>>>(Sloc, clog, Wo, Wob);
    k_fix<<<B_SZ * NH * NC, 256, 0, stream>>>(projb, Sloc, clog, yb, ybb);

    // phase 3: out_proj (BM=64 tile -> 512 blocks, 2+/CU, counted sched)
    {
        dim3 g(DM / 128, M_ROWS / 64);        // 8 x 64
        k_gemm_out<<<g, 256, 0, stream>>>(ybb, Wob, x, out, DI, DM);
    }
}

// Round 11
// 253.889 us; speedup vs baseline: 1.0554x; 1.0125x over previous
//
#include <hip/hip_runtime.h>
#include <math.h>

#define B_SZ     2
#define L_SEQ    2048
#define DM       1024      // D_MODEL
#define DP       4384      // D_PROJ (logical)
#define PS       4480      // proj padded stride (35 * 128)
#define DI       2048      // D_INNER
#define NH       32        // N_HEADS
#define HD       64        // HEAD_DIM
#define DS       128       // D_STATE
#define M_ROWS   (B_SZ * L_SEQ)   // 4096
#define QCH      64        // scan chunk length
#define NC       (L_SEQ / QCH)    // 32 chunks

typedef __bf16 bf16x8 __attribute__((ext_vector_type(8)));
typedef __bf16 bf16x4 __attribute__((ext_vector_type(4)));
typedef __bf16 bf16x2 __attribute__((ext_vector_type(2)));
typedef float  f32x4  __attribute__((ext_vector_type(4)));

// async global->LDS, 16B per lane. LDS dest is wave-uniform base + lane*16.
__device__ __forceinline__ void gload16(const void* g, void* l) {
    __builtin_amdgcn_global_load_lds(
        (const __attribute__((address_space(1))) unsigned int*)g,
        (__attribute__((address_space(3))) unsigned int*)l,
        16, 0, 0);
}

// ---------------------------------------------------------------------------
// Fused: f2b(Wp) [0..4383] + RMSNorm [4384..8479] + f2b(Wo) [8480..10527].
// R11: f2b(Wo) moved here from the carry kernel — it depends only on input
// Wo, so it runs at the front instead of serializing between k_chunk and
// k_fix (shortens the scan-phase critical path).
// ---------------------------------------------------------------------------
__global__ __launch_bounds__(256) void k_prep(const float* __restrict__ Wp,
                                              __bf16* __restrict__ Wpb,
                                              const float* __restrict__ x,
                                              const float* __restrict__ w,
                                              __bf16* __restrict__ xn,
                                              const float* __restrict__ Wo,
                                              __bf16* __restrict__ Wob) {
    int tid = threadIdx.x;
    if (blockIdx.x >= 8480) {
        int i = (blockIdx.x - 8480) * 256 + tid;   // < (DM*DI)/4
        float4 v = ((const float4*)Wo)[i];
        bf16x4 o = { (__bf16)v.x, (__bf16)v.y, (__bf16)v.z, (__bf16)v.w };
        ((bf16x4*)Wob)[i] = o;
        return;
    }
    if (blockIdx.x < 4384) {
        int i = blockIdx.x * 256 + tid;          // < (DP*DM)/4
        float4 v = ((const float4*)Wp)[i];
        bf16x4 o = { (__bf16)v.x, (__bf16)v.y, (__bf16)v.z, (__bf16)v.w };
        ((bf16x4*)Wpb)[i] = o;
        return;
    }
    int row = blockIdx.x - 4384;
    const float4* x4 = (const float4*)(x + (long)row * DM);
    float4 v = x4[tid];
    float ss = v.x * v.x + v.y * v.y + v.z * v.z + v.w * v.w;
    #pragma unroll
    for (int off = 32; off > 0; off >>= 1) ss += __shfl_xor(ss, off, 64);
    __shared__ float sred[4];
    if ((tid & 63) == 0) sred[tid >> 6] = ss;
    __syncthreads();
    float tot = sred[0] + sred[1] + sred[2] + sred[3];
    float scale = rsqrtf(tot * (1.0f / (float)DM) + 1e-6f);
    const float4* w4 = (const float4*)w;
    float4 wv = w4[tid];
    bf16x4 o = { (__bf16)(v.x * scale * wv.x), (__bf16)(v.y * scale * wv.y),
                 (__bf16)(v.z * scale * wv.z), (__bf16)(v.w * scale * wv.w) };
    ((bf16x4*)(xn + (long)row * DM))[tid] = o;
}

// ---------------------------------------------------------------------------
// in_proj GEMM (PROVEN schedule — 62.8us best-class, ~600 TF family ceiling):
// 128x128 tile, BK=64, double-buffered global_load_lds, source-XOR swizzle
// -> 0 bank conflicts, counted-vmcnt schedule, 2D-cluster XCD swizzle
// (R10: FETCH 88 -> 54 MB). Do not restructure (R3/R7 regressions).
// ---------------------------------------------------------------------------
__global__ __launch_bounds__(256) void k_gemm_bf(const __bf16* __restrict__ A,
                                                 const __bf16* __restrict__ W,
                                                 __bf16* __restrict__ Cb,
                                                 float* __restrict__ Dt,
                                                 int Nw, int K, int ldc) {
    __shared__ __align__(16) __bf16 As[2][128 * 64];
    __shared__ __align__(16) __bf16 Bs[2][128 * 64];
    int t = threadIdx.x;

    int gx = gridDim.x;
    int nwg = gx * gridDim.y;
    int orig = blockIdx.y * gx + blockIdx.x;
    int bx, by;
    if (gx == 35 && gridDim.y == 32) {
        int sy = orig & 7;          // XCD id
        int k  = orig >> 3;         // 0..139
        int st = k / 20;            // supertile column 0..6
        int wv = k % 20;            // position in 5x4 supertile
        bx = st * 5 + wv % 5;
        by = sy * 4 + wv / 5;
    } else {
        int wgid = (nwg & 7) ? orig : ((orig & 7) * (nwg >> 3) + (orig >> 3));
        bx = wgid % gx; by = wgid / gx;
    }
    int bm = by * 128, bn = bx * 128;

    int lane = t & 63, w = t >> 6;

    int rl = lane >> 3;                  // row-in-8 (== row & 7 of target row)
    int lc = (lane & 7) ^ rl;            // pre-swizzled source logical chunk
    int rbase = w * 32 + rl;
    const __bf16* Agp[4];
    const __bf16* Wgp[4];
    #pragma unroll
    for (int i = 0; i < 4; i++) {
        Agp[i] = A + (long)(bm + rbase + i * 8) * K + lc * 8;
        int rb = bn + rbase + i * 8; if (rb >= Nw) rb = Nw - 1;
        Wgp[i] = W + (long)rb * K + lc * 8;
    }

    int wm = (w & 1) * 64, wn = (w >> 1) * 64;
    int ln = lane & 15;
    int q  = lane >> 4;

    f32x4 acc[4][4] = {};

    int nst = K >> 6;

    #pragma unroll
    for (int i = 0; i < 4; i++) {
        gload16(Agp[i], As[0] + (w * 4 + i) * 512);
        gload16(Wgp[i], Bs[0] + (w * 4 + i) * 512);
    }

    int cur = 0;
    for (int s = 0; s < nst; ++s) {
        if (s + 1 < nst) {
            long k1 = (long)(s + 1) << 6;
            #pragma unroll
            for (int i = 0; i < 4; i++) {
                gload16(Agp[i] + k1, As[cur ^ 1] + (w * 4 + i) * 512);
                gload16(Wgp[i] + k1, Bs[cur ^ 1] + (w * 4 + i) * 512);
            }
            asm volatile("s_waitcnt vmcnt(8)" ::: "memory");  // s done; s+1 in flight
        } else {
            asm volatile("s_waitcnt vmcnt(0)" ::: "memory");  // final tile: drain
        }
        __builtin_amdgcn_sched_barrier(0);
        __builtin_amdgcn_s_barrier();        // tile s visible to all waves
        __builtin_amdgcn_sched_barrier(0);
        __builtin_amdgcn_s_setprio(1);

        const __bf16* Asc = As[cur];
        const __bf16* Bsc = Bs[cur];
        #pragma unroll
        for (int h = 0; h < 2; h++) {
            int ch = (4 * h + q);
            int koff = ((ch ^ (ln & 7)) << 3);   // (R&7)==(ln&7): wm,i*16 ≡ 0 mod 8
            bf16x8 af[4], bfr[4];
            #pragma unroll
            for (int i = 0; i < 4; i++)
                af[i]  = *(const bf16x8*)(Asc + (wm + ln + i * 16) * 64 + koff);
            #pragma unroll
            for (int j = 0; j < 4; j++)
                bfr[j] = *(const bf16x8*)(Bsc + (wn + ln + j * 16) * 64 + koff);
            #pragma unroll
            for (int i = 0; i < 4; i++)
                #pragma unroll
                for (int j = 0; j < 4; j++)
                    acc[i][j] = __builtin_amdgcn_mfma_f32_16x16x32_bf16(
                                    af[i], bfr[j], acc[i][j], 0, 0, 0);
        }
        __builtin_amdgcn_s_setprio(0);
        __builtin_amdgcn_sched_barrier(0);
        __builtin_amdgcn_s_barrier();        // reads done before buf reuse
        __builtin_amdgcn_sched_barrier(0);
        cur ^= 1;
    }

    int colbase = bn + wn + ln;
    #pragma unroll
    for (int i = 0; i < 4; i++) {
        #pragma unroll
        for (int r = 0; r < 4; r++) {
            int m = bm + wm + i * 16 + (lane >> 4) * 4 + r;
            long off = (long)m * ldc + colbase;
            #pragma unroll
            for (int j = 0; j < 4; j++) {
                float v = acc[i][j][r];
                Cb[off + j * 16] = (__bf16)v;
                int col = colbase + j * 16;
                if (col >= 4352 && col < 4384)
                    Dt[(long)m * 32 + (col - 4352)] = v;
            }
        }
    }
}

// ---------------------------------------------------------------------------
// out_proj GEMM: BM=64 x BN=128 tile, BK=64 -> 512 blocks (2/CU), counted
// vmcnt(6), 2D-cluster XCD swizzle. Unchanged from R10.
// ---------------------------------------------------------------------------
__global__ __launch_bounds__(256) void k_gemm_out(const __bf16* __restrict__ A,
                                                  const __bf16* __restrict__ W,
                                                  const float* __restrict__ resid,
                                                  float* __restrict__ Cf,
                                                  int K, int ldc) {
    __shared__ __align__(16) __bf16 As[2][64 * 64];
    __shared__ __align__(16) __bf16 Bs[2][128 * 64];
    int t = threadIdx.x;

    int gx = gridDim.x;                      // 8
    int nwg = gx * gridDim.y;                // 512
    int orig = blockIdx.y * gx + blockIdx.x;
    int bx, by;
    if (gx == 8 && gridDim.y == 64) {
        int xcd = orig & 7;
        int k   = orig >> 3;                 // 0..63
        int st  = k >> 3;                    // supertile 0..7
        int wv  = k & 7;                     // position in 2x4 supertile
        bx = (st & 3) * 2 + (wv & 1);
        by = xcd * 8 + (st >> 2) * 4 + (wv >> 1);
    } else {
        int wgid = (nwg & 7) ? orig : ((orig & 7) * (nwg >> 3) + (orig >> 3));
        bx = wgid % gx; by = wgid / gx;
    }
    int bm = by * 64, bn = bx * 128;

    int lane = t & 63, w = t >> 6;

    int rl = lane >> 3;
    int lc = (lane & 7) ^ rl;                // pre-swizzled source chunk
    const __bf16* Agp[2];
    const __bf16* Wgp[4];
    #pragma unroll
    for (int i = 0; i < 2; i++)
        Agp[i] = A + (long)(bm + w * 16 + i * 8 + rl) * K + lc * 8;
    #pragma unroll
    for (int i = 0; i < 4; i++)
        Wgp[i] = W + (long)(bn + w * 32 + i * 8 + rl) * K + lc * 8;

    int wm = (w & 1) * 32, wn = (w >> 1) * 64;
    int ln = lane & 15;
    int q  = lane >> 4;

    f32x4 acc[2][4] = {};

    int nst = K >> 6;                        // 32

    #pragma unroll
    for (int i = 0; i < 2; i++) gload16(Agp[i], As[0] + (w * 2 + i) * 512);
    #pragma unroll
    for (int i = 0; i < 4; i++) gload16(Wgp[i], Bs[0] + (w * 4 + i) * 512);

    int cur = 0;
    for (int s = 0; s < nst; ++s) {
        if (s + 1 < nst) {
            long k1 = (long)(s + 1) << 6;
            #pragma unroll
            for (int i = 0; i < 2; i++)
                gload16(Agp[i] + k1, As[cur ^ 1] + (w * 2 + i) * 512);
            #pragma unroll
            for (int i = 0; i < 4; i++)
                gload16(Wgp[i] + k1, Bs[cur ^ 1] + (w * 4 + i) * 512);
            asm volatile("s_waitcnt vmcnt(6)" ::: "memory");
        } else {
            asm volatile("s_waitcnt vmcnt(0)" ::: "memory");
        }
        __builtin_amdgcn_sched_barrier(0);
        __builtin_amdgcn_s_barrier();
        __builtin_amdgcn_sched_barrier(0);
        __builtin_amdgcn_s_setprio(1);

        const __bf16* Asc = As[cur];
        const __bf16* Bsc = Bs[cur];
        #pragma unroll
        for (int h = 0; h < 2; h++) {
            int ch = (4 * h + q);
            int koff = ((ch ^ (ln & 7)) << 3);
            bf16x8 af[2], bfr[4];
            #pragma unroll
            for (int i = 0; i < 2; i++)
                af[i]  = *(const bf16x8*)(Asc + (wm + ln + i * 16) * 64 + koff);
            #pragma unroll
            for (int j = 0; j < 4; j++)
                bfr[j] = *(const bf16x8*)(Bsc + (wn + ln + j * 16) * 64 + koff);
            #pragma unroll
            for (int i = 0; i < 2; i++)
                #pragma unroll
                for (int j = 0; j < 4; j++)
                    acc[i][j] = __builtin_amdgcn_mfma_f32_16x16x32_bf16(
                                    af[i], bfr[j], acc[i][j], 0, 0, 0);
        }
        __builtin_amdgcn_s_setprio(0);
        __builtin_amdgcn_sched_barrier(0);
        __builtin_amdgcn_s_barrier();
        __builtin_amdgcn_sched_barrier(0);
        cur ^= 1;
    }

    int colbase = bn + wn + ln;
    #pragma unroll
    for (int i = 0; i < 2; i++) {
        #pragma unroll
        for (int r = 0; r < 4; r++) {
            int m = bm + wm + i * 16 + (lane >> 4) * 4 + r;
            long off = (long)m * ldc + colbase;
            #pragma unroll
            for (int j = 0; j < 4; j++) {
                float v = acc[i][j][r] + resid[off + j * 16];
                Cf[off + j * 16] = v;
            }
        }
    }
}

// ---------------------------------------------------------------------------
// Phase A (MFMA) fused conv+SiLU+dt/cumlog+D-term. B/C staging via
// global_load_lds with linear-XOR layout (R10, refcheck'd). Epilogues in R8
// scalar form (R9 LDS-bounce regressed). Unchanged from R10.
// ---------------------------------------------------------------------------
__global__ __launch_bounds__(256) void k_chunk(const __bf16* __restrict__ projb,
                                               const float* __restrict__ dtraw,
                                               const float* __restrict__ cw,
                                               const float* __restrict__ cb,
                                               const float* __restrict__ A_log,
                                               const float* __restrict__ dt_bias,
                                               const float* __restrict__ Dv,
                                               float* __restrict__ clog,
                                               __bf16* __restrict__ yssm,
                                               __bf16* __restrict__ Sloc) {
    int blk = blockIdx.x;
    int c  = blk & 31;
    int hh = (blk >> 5) & 31;
    int b  = blk >> 10;
    int tid = threadIdx.x;
    long rowbase = (long)b * L_SEQ + c * QCH;

    __shared__ __align__(16) __bf16 sB[64 * 128];    // B_chunk [s][128] linear-XOR
    __shared__ __align__(16) __bf16 sU[128 * 72];    // ph1: C [t][128] linear-XOR; ph2: B^T [n][s] str72
    __shared__ __align__(16) __bf16 sXT[64 * 72];    // dtx^T [p][s]
    __shared__ __align__(16) __bf16 sXCM[67 * 72];   // ph1: raw x [ss][p]; ph2 overlay: M [t][s]
    __shared__ __align__(16) __bf16 sXCo[64 * 72];   // conv-silu output xc [t][p]
    __shared__ float sCW[256];
    __shared__ float sCB[64];
    __shared__ float sclog[64];
    __shared__ float sdt[64];
    __shared__ float sw[64];

    int lane = tid & 63, w = tid >> 6;

    // ---- stage B, C via gload16: wave w, call r stages rows r*16+w*4..+3 ----
    {
        int rl4 = lane >> 4;
        int pc  = lane & 15;
        #pragma unroll
        for (int r = 0; r < 4; r++) {
            int row0 = r * 16 + w * 4;
            int row  = row0 + rl4;
            int lc2  = (pc ^ (row & 7)) * 8;
            const __bf16* pr = projb + (rowbase + row) * (long)PS;
            gload16(pr + 4096 + lc2, sB + row0 * 128);
            gload16(pr + 4224 + lc2, sU + row0 * 128);
        }
    }
    // ---- stage raw x rows ss=0..66 (t = ss-3; zero before seq start) ----
    #pragma unroll
    for (int j = 0; j < 3; j++) {
        int off = j * 256 + tid;          // need 536 = 67 rows * 8 chunks
        if (off < 536) {
            int ss = off >> 3;
            int p8 = (off & 7) * 8;
            bf16x8 xv;
            #pragma unroll
            for (int k = 0; k < 8; k++) xv[k] = (__bf16)0.0f;
            if (c > 0 || ss >= 3)
                xv = *(const bf16x8*)(projb + (rowbase + ss - 3) * (long)PS + DI + hh * HD + p8);
            *(bf16x8*)&sXCM[ss * 72 + p8] = xv;
        }
    }
    sCW[tid] = cw[hh * 256 + tid];
    if (tid < 64) sCB[tid] = cb[hh * 64 + tid];

    // ---- wave 0: dt = softplus (fp32 dtraw), clog = inclusive scan ----
    if (tid < 64) {
        float xr = dtraw[(rowbase + tid) * 32 + hh] + dt_bias[hh];
        float dt = (xr > 20.0f) ? xr : log1pf(expf(xr));
        float la = -expf(A_log[hh]);
        float v = la * dt;
        #pragma unroll
        for (int off = 1; off < 64; off <<= 1) {
            float u = __shfl_up(v, off, 64);
            if (tid >= off) v += u;
        }
        sdt[tid] = dt;
        sclog[tid] = v;
        clog[(rowbase + tid) * NH + hh] = v;
    }
    __syncthreads();   // drains vmcnt(0): sB/sU staged; scan/conv inputs ready

    // ---- conv K=4 + SiLU (vectorized): thread owns fixed p8, two s rows ----
    {
        int p8 = (tid & 7) * 8;
        float wreg[8][4], breg[8];
        #pragma unroll
        for (int e = 0; e < 8; e++) {
            breg[e] = sCB[p8 + e];
            #pragma unroll
            for (int j = 0; j < 4; j++) wreg[e][j] = sCW[(p8 + e) * 4 + j];
        }
        #pragma unroll
        for (int i = 0; i < 2; i++) {
            int s = i * 32 + (tid >> 3);
            bf16x8 r0 = *(const bf16x8*)&sXCM[(s + 0) * 72 + p8];
            bf16x8 r1 = *(const bf16x8*)&sXCM[(s + 1) * 72 + p8];
            bf16x8 r2 = *(const bf16x8*)&sXCM[(s + 2) * 72 + p8];
            bf16x8 r3 = *(const bf16x8*)&sXCM[(s + 3) * 72 + p8];
            float dts = sdt[s];
            bf16x8 oc;
            #pragma unroll
            for (int e = 0; e < 8; e++) {
                float acc = breg[e];
                acc = fmaf(wreg[e][0], (float)r0[e], acc);
                acc = fmaf(wreg[e][1], (float)r1[e], acc);
                acc = fmaf(wreg[e][2], (float)r2[e], acc);
                acc = fmaf(wreg[e][3], (float)r3[e], acc);
                float xc = acc / (1.0f + expf(-acc));
                oc[e] = (__bf16)xc;
                sXT[(p8 + e) * 72 + s] = (__bf16)(dts * xc);
            }
            *(bf16x8*)&sXCo[s * 72 + p8] = oc;
        }
    }
    if (tid < 64) sw[tid] = expf(sclog[63] - sclog[tid]);
    __syncthreads();   // conv reads of sXCM done -> sXCM reusable as sM

    int ln = lane & 15;
    int quad = lane >> 4;
    int kc = quad * 8;

    // ---- G = C @ B^T  (linear-XOR reads: chunk = quad + 4*k0, ^ (ln&7)) ----
    bf16x8 caf[4];
    #pragma unroll
    for (int k0 = 0; k0 < 4; k0++)
        caf[k0] = *(const bf16x8*)&sU[(16 * w + ln) * 128 + (((quad + 4 * k0) ^ (ln & 7)) << 3)];
    f32x4 g[4] = {};
    #pragma unroll
    for (int j = 0; j < 4; j++)
        #pragma unroll
        for (int k0 = 0; k0 < 4; k0++) {
            bf16x8 bf_ = *(const bf16x8*)&sB[(16 * j + ln) * 128 + (((quad + 4 * k0) ^ (ln & 7)) << 3)];
            g[j] = __builtin_amdgcn_mfma_f32_16x16x32_bf16(caf[k0], bf_, g[j], 0, 0, 0);
        }

    // ---- M[t,s] = (s<=t) ? exp(clog_t - clog_s) * G : 0 -> sXCM overlay ----
    {
        int trow = 16 * w + quad * 4;
        #pragma unroll
        for (int r = 0; r < 4; r++) {
            int t = trow + r;
            float ct = sclog[t];
            #pragma unroll
            for (int j = 0; j < 4; j++) {
                int s = 16 * j + ln;
                float v = (s <= t) ? g[j][r] * expf(ct - sclog[s]) : 0.0f;
                sXCM[t * 72 + s] = (__bf16)v;
            }
        }
    }
    __syncthreads();   // sM complete; sU (C) now dead

    // ---- transpose sB -> sU as B^T [n][s] (stride 72); XOR source chunk ----
    #pragma unroll
    for (int j = 0; j < 4; j++) {
        int s  = tid & 63;
        int ch = j * 4 + (tid >> 6);
        bf16x8 v = *(const bf16x8*)&sB[s * 128 + ((ch ^ (s & 7)) << 3)];
        int n8 = ch * 8;
        #pragma unroll
        for (int k = 0; k < 8; k++) sU[(n8 + k) * 72 + s] = v[k];
    }

    // ---- Y = M @ DTX + D[h]*xc  (bf16 out) ----
    {
        float Dh = Dv[hh];
        bf16x8 maf[2];
        #pragma unroll
        for (int k0 = 0; k0 < 2; k0++)
            maf[k0] = *(const bf16x8*)&sXCM[(16 * w + ln) * 72 + kc + k0 * 32];
        f32x4 y[4] = {};
        #pragma unroll
        for (int j = 0; j < 4; j++)
            #pragma unroll
            for (int k0 = 0; k0 < 2; k0++) {
                bf16x8 xf = *(const bf16x8*)&sXT[(16 * j + ln) * 72 + kc + k0 * 32];
                y[j] = __builtin_amdgcn_mfma_f32_16x16x32_bf16(maf[k0], xf, y[j], 0, 0, 0);
            }
        #pragma unroll
        for (int j = 0; j < 4; j++)
            #pragma unroll
            for (int r = 0; r < 4; r++) {
                int t = 16 * w + quad * 4 + r;
                int p = 16 * j + ln;
                float v = y[j][r] + Dh * (float)sXCo[t * 72 + p];
                yssm[(rowbase + t) * DI + hh * HD + p] = (__bf16)v;
            }
    }
    __syncthreads();   // sU (B^T) complete

    // ---- S_loc[p,n] = sum_s w_s * dtx[s,p] * B[s,n]  (bf16 out) ----
    {
        bf16x8 xaf[2];
        #pragma unroll
        for (int k0 = 0; k0 < 2; k0++) {
            bf16x8 raw = *(const bf16x8*)&sXT[(16 * w + ln) * 72 + kc + k0 * 32];
            bf16x8 sc;
            #pragma unroll
            for (int jj = 0; jj < 8; jj++) {
                int s = kc + k0 * 32 + jj;
                sc[jj] = (__bf16)((float)raw[jj] * sw[s]);
            }
            xaf[k0] = sc;
        }
        f32x4 sacc[8] = {};
        #pragma unroll
        for (int j = 0; j < 8; j++)
            #pragma unroll
            for (int k0 = 0; k0 < 2; k0++) {
                bf16x8 btf = *(const bf16x8*)&sU[(16 * j + ln) * 72 + kc + k0 * 32];
                sacc[j] = __builtin_amdgcn_mfma_f32_16x16x32_bf16(xaf[k0], btf, sacc[j], 0, 0, 0);
            }
        long sbase = ((long)(b * NH + hh) * NC + c) * (HD * DS);
        #pragma unroll
        for (int j = 0; j < 8; j++)
            #pragma unroll
            for (int r = 0; r < 4; r++) {
                int p = 16 * w + quad * 4 + r;
                int n = 16 * j + ln;
                Sloc[sbase + p * DS + n] = (__bf16)sacc[j][r];
            }
    }
}

// ---------------------------------------------------------------------------
// Carry-only (R11: f2b(Wo) moved to k_prep). 512 blocks; each thread owns a
// bf16x4 (8B/lane — coalescing sweet spot, was bf16x2 4B). lam table once
// per block in LDS; serial chain software-pipelined (S[c+1] prefetched
// before the T[c] store). 2048 waves = 8/CU — ample TLP.
// ---------------------------------------------------------------------------
__global__ __launch_bounds__(256) void k_carry(__bf16* __restrict__ Sloc,
                                               const float* __restrict__ clog) {
    int tid = threadIdx.x;
    int idx = blockIdx.x * 256 + tid;        // < 131072 (one bf16x4 each)
    int n4 = idx & 31;                       // quad index: n = 4*n4 .. 4*n4+3
    int p  = (idx >> 5) & 63;
    int hh = (idx >> 11) & 31;               // block-uniform
    int b  = idx >> 16;                      // block-uniform

    __shared__ float slam[NC];
    if (tid < NC)
        slam[tid] = expf(clog[((long)b * L_SEQ + tid * QCH + QCH - 1) * NH + hh]);
    __syncthreads();

    long base = ((long)(b * NH + hh) * NC) * (HD * DS) + p * DS + n4 * 4;
    const long cstride = HD * DS;
    float T0 = 0.0f, T1 = 0.0f, T2 = 0.0f, T3 = 0.0f;
    long a = base;
    bf16x4 Sv = *(const bf16x4*)&Sloc[a];
    for (int c = 0; c < NC; c++) {
        bf16x4 Sn;
        if (c + 1 < NC) Sn = *(const bf16x4*)&Sloc[a + cstride];
        float lam = slam[c];
        bf16x4 Tv = { (__bf16)T0, (__bf16)T1, (__bf16)T2, (__bf16)T3 };
        *(bf16x4*)&Sloc[a] = Tv;
        T0 = fmaf(T0, lam, (float)Sv[0]);
        T1 = fmaf(T1, lam, (float)Sv[1]);
        T2 = fmaf(T2, lam, (float)Sv[2]);
        T3 = fmaf(T3, lam, (float)Sv[3]);
        Sv = Sn;
        a += cstride;
    }
}

// ---------------------------------------------------------------------------
// Phase C + gate (MFMA): Ycorr = C_chunk @ Hin^T, then
// yg = (yb + exp(clog_t)*Ycorr) * silu(z), bf16 out. R8 form. Unchanged.
// ---------------------------------------------------------------------------
__global__ __launch_bounds__(256, 4) void k_fix(const __bf16* __restrict__ projb,
                                                const __bf16* __restrict__ Sloc,
                                                const float* __restrict__ clog,
                                                const __bf16* __restrict__ yb,
                                                __bf16* __restrict__ yg) {
    int blk = blockIdx.x;
    int c  = blk & 31;
    int hh = (blk >> 5) & 31;
    int b  = blk >> 10;

    __shared__ __align__(16) __bf16 sC[64 * 136];   // C [t][n]
    __shared__ __align__(16) __bf16 sH[64 * 136];   // Hin [p][n]
    __shared__ float sP[64];

    int tid = threadIdx.x;
    long hbase = ((long)(b * NH + hh) * NC + c) * (HD * DS);
    long rowbase = (long)b * L_SEQ + c * QCH;

    #pragma unroll
    for (int j = 0; j < 4; j++) {
        int off = j * 256 + tid;          // 1024 bf16x8
        int t  = off >> 4;
        int n8 = (off & 15) * 8;
        *(bf16x8*)&sC[t * 136 + n8] =
            *(const bf16x8*)(projb + (rowbase + t) * (long)PS + 4224 + n8);
    }
    #pragma unroll
    for (int j = 0; j < 4; j++) {
        int off = j * 256 + tid;          // 1024 bf16x8 = 64 p-rows * 16
        int p  = off >> 4;
        int n8 = (off & 15) * 8;
        *(bf16x8*)&sH[p * 136 + n8] = *(const bf16x8*)&Sloc[hbase + (long)off * 8];
    }
    if (tid < 64) sP[tid] = expf(clog[(rowbase + tid) * NH + hh]);
    __syncthreads();

    int lane = tid & 63, w = tid >> 6;
    int ln = lane & 15;
    int quad = lane >> 4;
    int kc = quad * 8;

    bf16x8 caf[4];
    #pragma unroll
    for (int k0 = 0; k0 < 4; k0++)
        caf[k0] = *(const bf16x8*)&sC[(16 * w + ln) * 136 + kc + k0 * 32];
    f32x4 acc4[4] = {};
    #pragma unroll
    for (int j = 0; j < 4; j++)
        #pragma unroll
        for (int k0 = 0; k0 < 4; k0++) {
            bf16x8 hf = *(const bf16x8*)&sH[(16 * j + ln) * 136 + kc + k0 * 32];
            acc4[j] = __builtin_amdgcn_mfma_f32_16x16x32_bf16(caf[k0], hf, acc4[j], 0, 0, 0);
        }

    #pragma unroll
    for (int j = 0; j < 4; j++)
        #pragma unroll
        for (int r = 0; r < 4; r++) {
            int t = 16 * w + quad * 4 + r;
            int p = 16 * j + ln;
            long row = rowbase + t;
            long yoff = row * DI + hh * HD + p;
            float pm = sP[t];
            float z = (float)projb[row * (long)PS + hh * HD + p];
            float o = ((float)yb[yoff] + pm * acc4[j][r]) * (z / (1.0f + expf(-z)));
            yg[yoff] = (__bf16)o;
        }
}

// ---------------------------------------------------------------------------
extern "C" void kernel_launch(void* const* d_in, const int* in_sizes, int n_in,
                              void* d_out, int out_size, void* d_ws, size_t ws_size,
                              hipStream_t stream) {
    const float* x       = (const float*)d_in[0];
    const float* norm_w  = (const float*)d_in[1];
    const float* Wp      = (const float*)d_in[2];   // (4384, 1024)
    const float* cw      = (const float*)d_in[3];
    const float* cb      = (const float*)d_in[4];
    const float* A_log   = (const float*)d_in[5];
    const float* Dv      = (const float*)d_in[6];
    const float* dt_bias = (const float*)d_in[7];
    const float* Wo      = (const float*)d_in[8];   // (1024, 2048)
    float* out = (float*)d_out;

    // workspace (float units):
    float* ws     = (float*)d_ws;
    __bf16* projb = (__bf16*)ws;              //  9,175,040 fl (18,350,080 bf16)
    float* dtraw  = ws    + 9175040;          //    131,072
    float* clog   = dtraw + 131072;           //    131,072
    float* ybh    = clog  + 131072;           //  4,194,304 fl (yb bf16)
    float* ybf    = ybh   + 4194304;          //  4,194,304 fl (ybb bf16)
    float* wob_s  = ybf   + 4194304;          //  1,048,576 fl (Wob bf16)
    float* U      = wob_s + 1048576;          // 16,777,216 (Sloc bf16 uses half)
    // total 35,651,584 floats = 142.6 MB

    __bf16* xnb  = (__bf16*)U;
    __bf16* Wpb  = (__bf16*)(U + 2097152);
    __bf16* Sloc = (__bf16*)U;                // 33,554,432 bf16 fits the slot
    __bf16* Wob  = (__bf16*)wob_s;
    __bf16* ybb  = (__bf16*)ybf;
    __bf16* yb   = (__bf16*)ybh;

    // phase 1: f2b(Wp) + rmsnorm + f2b(Wo) fused, then in_proj GEMM
    k_prep<<<4384 + M_ROWS + 2048, 256, 0, stream>>>(Wp, Wpb, x, norm_w, xnb,
                                                     Wo, Wob);
    {
        dim3 g(PS / 128, M_ROWS / 128);       // 35 x 32
        k_gemm_bf<<<g, 256, 0, stream>>>(xnb, Wpb, projb, dtraw, DP, DM, PS);
    }

    // phase 2: chunked scan (Sloc overwrites xnb/Wpb — dead)
    k_chunk<<<B_SZ * NH * NC, 256, 0, stream>>>(projb, dtraw, cw, cb, A_log,
                                                dt_bias, Dv, clog, yb, Sloc);
    k_carry<<<512, 256, 0, stream>>>(Sloc, clog);
    k_fix<<<B_SZ * NH * NC, 256, 0, stream>>>(projb, Sloc, clog, yb, ybb);

    // phase 3: out_proj (BM=64 tile -> 512 blocks, 2+/CU, counted sched)
    {
        dim3 g(DM / 128, M_ROWS / 64);        // 8 x 64
        k_gemm_out<<<g, 256, 0, stream>>>(ybb, Wob, x, out, DI, DM);
    }
}